// Round 2
// baseline (328.409 us; speedup 1.0000x reference)
//
#include <hip/hip_runtime.h>
#include <hip/hip_bf16.h>
#include <stdint.h>

#define NPTS 262144
#define TBL 524288u
#define TBL_MASK 524287u

// LDS float offsets (all multiples of 4 for float4 loads)
#define O_WD1 0
#define O_BD1 2048
#define O_WD2 2112
#define O_BD2 3136
#define O_WC1 3152
#define O_BC1 5200
#define O_WC2 5264
#define O_BC2 9360
#define O_WC3 9424
#define O_BC3 9616
#define LDS_FLOATS 9620

__global__ void __launch_bounds__(256) nerf_fused(
    const float* __restrict__ g_pos,
    const float* __restrict__ g_dir,
    const float* __restrict__ g_tab,
    const float* __restrict__ g_wd1,
    const float* __restrict__ g_bd1,
    const float* __restrict__ g_wd2,
    const float* __restrict__ g_bd2,
    const float* __restrict__ g_wc1,
    const float* __restrict__ g_bc1,
    const float* __restrict__ g_wc2,
    const float* __restrict__ g_bc2,
    const float* __restrict__ g_wc3,
    const float* __restrict__ g_bc3,
    float* __restrict__ g_out)
{
    __shared__ float sw[LDS_FLOATS];
    const int tid = threadIdx.x;
    for (int i = tid; i < 2048; i += 256) sw[O_WD1 + i] = g_wd1[i];
    for (int i = tid; i < 64;   i += 256) sw[O_BD1 + i] = g_bd1[i];
    for (int i = tid; i < 1024; i += 256) sw[O_WD2 + i] = g_wd2[i];
    for (int i = tid; i < 16;   i += 256) sw[O_BD2 + i] = g_bd2[i];
    for (int i = tid; i < 2048; i += 256) sw[O_WC1 + i] = g_wc1[i];
    for (int i = tid; i < 64;   i += 256) sw[O_BC1 + i] = g_bc1[i];
    for (int i = tid; i < 4096; i += 256) sw[O_WC2 + i] = g_wc2[i];
    for (int i = tid; i < 64;   i += 256) sw[O_BC2 + i] = g_bc2[i];
    for (int i = tid; i < 192;  i += 256) sw[O_WC3 + i] = g_wc3[i];
    for (int i = tid; i < 3;    i += 256) sw[O_BC3 + i] = g_bc3[i];
    __syncthreads();

    const int p = blockIdx.x * 256 + tid;
    const float px = g_pos[3 * p + 0];
    const float py = g_pos[3 * p + 1];
    const float pz = g_pos[3 * p + 2];

    // floor(16 * growth^l), growth = 64^(1/15)
    constexpr float scale[16] = {16.f, 21.f, 27.f, 36.f, 48.f, 64.f, 84.f, 111.f,
                                 147.f, 194.f, 256.f, 337.f, 445.f, 588.f, 776.f, 1024.f};

    // ---------- hash encoding ----------
    float enc[32];
    #pragma unroll
    for (int l = 0; l < 16; ++l) {
        const float s = scale[l];
        const float sx = px * s, sy = py * s, sz = pz * s;
        const float fx = floorf(sx), fy = floorf(sy), fz = floorf(sz);
        const float cx = ceilf(sx),  cy = ceilf(sy),  cz = ceilf(sz);
        const float tx = sx - fx, ty = sy - fy, tz = sz - fz;
        const uint32_t x0 = (uint32_t)fx, x1 = (uint32_t)cx;
        const uint32_t hy0 = (uint32_t)fy * 2654435761u, hy1 = (uint32_t)cy * 2654435761u;
        const uint32_t hz0 = (uint32_t)fz * 805459861u,  hz1 = (uint32_t)cz * 805459861u;
        const uint32_t base = (uint32_t)l * TBL;
        float e0 = 0.f, e1 = 0.f;
        #pragma unroll
        for (int c = 0; c < 8; ++c) {
            const uint32_t hx = (c & 1) ? x1 : x0;
            const uint32_t hy = (c & 2) ? hy1 : hy0;
            const uint32_t hz = (c & 4) ? hz1 : hz0;
            const uint32_t idx = ((hx ^ hy ^ hz) & TBL_MASK) + base;
            const float2 fv = *reinterpret_cast<const float2*>(g_tab + 2 * (size_t)idx);
            const float wgt = ((c & 1) ? tx : 1.f - tx)
                            * ((c & 2) ? ty : 1.f - ty)
                            * ((c & 4) ? tz : 1.f - tz);
            e0 = fmaf(fv.x, wgt, e0);
            e1 = fmaf(fv.y, wgt, e1);
        }
        enc[2 * l]     = e0;
        enc[2 * l + 1] = e1;
    }

    // ---------- density MLP: h = relu(enc @ wd1 + bd1) ----------
    float h[64];
    #pragma unroll
    for (int jj = 0; jj < 16; ++jj) {
        float4 acc = *reinterpret_cast<const float4*>(&sw[O_BD1 + jj * 4]);
        #pragma unroll
        for (int k = 0; k < 32; ++k) {
            const float4 wv = *reinterpret_cast<const float4*>(&sw[O_WD1 + k * 64 + jj * 4]);
            acc.x = fmaf(enc[k], wv.x, acc.x);
            acc.y = fmaf(enc[k], wv.y, acc.y);
            acc.z = fmaf(enc[k], wv.z, acc.z);
            acc.w = fmaf(enc[k], wv.w, acc.w);
        }
        h[jj * 4 + 0] = fmaxf(acc.x, 0.f);
        h[jj * 4 + 1] = fmaxf(acc.y, 0.f);
        h[jj * 4 + 2] = fmaxf(acc.z, 0.f);
        h[jj * 4 + 3] = fmaxf(acc.w, 0.f);
    }

    // ---------- density = h @ wd2 + bd2 (no activation) ----------
    float dens[16];
    #pragma unroll
    for (int jj = 0; jj < 4; ++jj) {
        float4 acc = *reinterpret_cast<const float4*>(&sw[O_BD2 + jj * 4]);
        #pragma unroll
        for (int k = 0; k < 64; ++k) {
            const float4 wv = *reinterpret_cast<const float4*>(&sw[O_WD2 + k * 16 + jj * 4]);
            acc.x = fmaf(h[k], wv.x, acc.x);
            acc.y = fmaf(h[k], wv.y, acc.y);
            acc.z = fmaf(h[k], wv.z, acc.z);
            acc.w = fmaf(h[k], wv.w, acc.w);
        }
        dens[jj * 4 + 0] = acc.x;
        dens[jj * 4 + 1] = acc.y;
        dens[jj * 4 + 2] = acc.z;
        dens[jj * 4 + 3] = acc.w;
    }

    // write density output (16 f32 per point)
    {
        float4* outp = reinterpret_cast<float4*>(g_out + (size_t)p * 16);
        #pragma unroll
        for (int q = 0; q < 4; ++q) {
            outp[q] = make_float4(dens[4 * q], dens[4 * q + 1], dens[4 * q + 2], dens[4 * q + 3]);
        }
    }

    // ---------- SH encode of direction ----------
    const float dx = g_dir[3 * p + 0];
    const float dy = g_dir[3 * p + 1];
    const float dz = g_dir[3 * p + 2];
    const float xx = dx * dx, yy = dy * dy, zz = dz * dz;

    float xin[32];
    #pragma unroll
    for (int i = 0; i < 16; ++i) xin[i] = dens[i];
    xin[16] = 0.28209479177387814f;
    xin[17] = 0.4886025119029199f * dy;
    xin[18] = 0.4886025119029199f * dz;
    xin[19] = 0.4886025119029199f * dx;
    xin[20] = 1.0925484305920792f * dx * dy;
    xin[21] = 1.0925484305920792f * dy * dz;
    xin[22] = 0.9461746957575601f * zz - 0.31539156525252f;
    xin[23] = 1.0925484305920792f * dx * dz;
    xin[24] = 0.5462742152960396f * (xx - yy);
    xin[25] = 0.5900435899266435f * dy * (3.f * xx - yy);
    xin[26] = 2.890611442640554f * dx * dy * dz;
    xin[27] = 0.4570457994644658f * dy * (5.f * zz - 1.f);
    xin[28] = 0.3731763325901154f * dz * (5.f * zz - 3.f);
    xin[29] = 0.4570457994644658f * dx * (5.f * zz - 1.f);
    xin[30] = 1.445305721320277f * dz * (xx - yy);
    xin[31] = 0.5900435899266435f * dx * (xx - 3.f * yy);

    // ---------- color layer 1: c1 = relu(xin @ wc1 + bc1) ----------
    float c1[64];
    #pragma unroll
    for (int jj = 0; jj < 16; ++jj) {
        float4 acc = *reinterpret_cast<const float4*>(&sw[O_BC1 + jj * 4]);
        #pragma unroll
        for (int k = 0; k < 32; ++k) {
            const float4 wv = *reinterpret_cast<const float4*>(&sw[O_WC1 + k * 64 + jj * 4]);
            acc.x = fmaf(xin[k], wv.x, acc.x);
            acc.y = fmaf(xin[k], wv.y, acc.y);
            acc.z = fmaf(xin[k], wv.z, acc.z);
            acc.w = fmaf(xin[k], wv.w, acc.w);
        }
        c1[jj * 4 + 0] = fmaxf(acc.x, 0.f);
        c1[jj * 4 + 1] = fmaxf(acc.y, 0.f);
        c1[jj * 4 + 2] = fmaxf(acc.z, 0.f);
        c1[jj * 4 + 3] = fmaxf(acc.w, 0.f);
    }

    // ---------- color layer 2: c2 = relu(c1 @ wc2 + bc2) ----------
    float c2[64];
    #pragma unroll
    for (int jj = 0; jj < 16; ++jj) {
        float4 acc = *reinterpret_cast<const float4*>(&sw[O_BC2 + jj * 4]);
        #pragma unroll
        for (int k = 0; k < 64; ++k) {
            const float4 wv = *reinterpret_cast<const float4*>(&sw[O_WC2 + k * 64 + jj * 4]);
            acc.x = fmaf(c1[k], wv.x, acc.x);
            acc.y = fmaf(c1[k], wv.y, acc.y);
            acc.z = fmaf(c1[k], wv.z, acc.z);
            acc.w = fmaf(c1[k], wv.w, acc.w);
        }
        c2[jj * 4 + 0] = fmaxf(acc.x, 0.f);
        c2[jj * 4 + 1] = fmaxf(acc.y, 0.f);
        c2[jj * 4 + 2] = fmaxf(acc.z, 0.f);
        c2[jj * 4 + 3] = fmaxf(acc.w, 0.f);
    }

    // ---------- color layer 3 + sigmoid ----------
    float a0 = sw[O_BC3 + 0], a1 = sw[O_BC3 + 1], a2 = sw[O_BC3 + 2];
    #pragma unroll
    for (int k = 0; k < 64; ++k) {
        const float hv = c2[k];
        a0 = fmaf(hv, sw[O_WC3 + k * 3 + 0], a0);
        a1 = fmaf(hv, sw[O_WC3 + k * 3 + 1], a1);
        a2 = fmaf(hv, sw[O_WC3 + k * 3 + 2], a2);
    }
    const float s0 = 1.f / (1.f + expf(-a0));
    const float s1 = 1.f / (1.f + expf(-a1));
    const float s2 = 1.f / (1.f + expf(-a2));

    float* cp = g_out + (size_t)NPTS * 16 + (size_t)p * 3;
    cp[0] = s0;
    cp[1] = s1;
    cp[2] = s2;
}

extern "C" void kernel_launch(void* const* d_in, const int* in_sizes, int n_in,
                              void* d_out, int out_size, void* d_ws, size_t ws_size,
                              hipStream_t stream) {
    nerf_fused<<<NPTS / 256, 256, 0, stream>>>(
        (const float*)d_in[0],   // position
        (const float*)d_in[1],   // direction
        (const float*)d_in[2],   // hash_table
        (const float*)d_in[3],   // w_d1
        (const float*)d_in[4],   // b_d1
        (const float*)d_in[5],   // w_d2
        (const float*)d_in[6],   // b_d2
        (const float*)d_in[7],   // w_c1
        (const float*)d_in[8],   // b_c1
        (const float*)d_in[9],   // w_c2
        (const float*)d_in[10],  // b_c2
        (const float*)d_in[11],  // w_c3
        (const float*)d_in[12],  // b_c3
        (float*)d_out);
}

// Round 4
// 213.727 us; speedup vs baseline: 1.5366x; 1.5366x over previous
//
#include <hip/hip_runtime.h>
#include <stdint.h>

#define NPTS 262144
#define TBL 524288u
#define TBL_MASK 524287u

typedef __attribute__((ext_vector_type(8))) _Float16 half8;
typedef __attribute__((ext_vector_type(4))) float f32x4;

__device__ __forceinline__ uint16_t f2h(float f) {
    _Float16 h = (_Float16)f;               // v_cvt_f16_f32, RNE
    return __builtin_bit_cast(uint16_t, h);
}
__device__ __forceinline__ uint32_t pack2(float lo, float hi) {
    return (uint32_t)f2h(lo) | ((uint32_t)f2h(hi) << 16);
}

// B-fragment for 16x16x32 f16 MFMA from row-major [K][N] f32 weights:
// lane l holds B[k = kofs + (l>>4)*8 + j][n = nofs + (l&15)], j = 0..7
__device__ __forceinline__ half8 bfrag(const float* __restrict__ W, int N, int kofs, int nofs, int l) {
    const int k0 = kofs + ((l >> 4) << 3);
    const float* p = W + (size_t)k0 * N + (nofs + (l & 15));
    union { uint32_t u[4]; half8 s; } r;
    r.u[0] = pack2(p[0 * N], p[1 * N]);
    r.u[1] = pack2(p[2 * N], p[3 * N]);
    r.u[2] = pack2(p[4 * N], p[5 * N]);
    r.u[3] = pack2(p[6 * N], p[7 * N]);
    return r.s;
}

// wc3 is [64][3]; pad N to 16 with zeros
__device__ __forceinline__ half8 bfrag3(const float* __restrict__ W, int kofs, int l) {
    const int k0 = kofs + ((l >> 4) << 3);
    const int n = l & 15;
    union { uint32_t u[4]; half8 s; } r;
    if (n < 3) {
        const float* p = W + (size_t)k0 * 3 + n;
        r.u[0] = pack2(p[0],  p[3]);
        r.u[1] = pack2(p[6],  p[9]);
        r.u[2] = pack2(p[12], p[15]);
        r.u[3] = pack2(p[18], p[21]);
    } else {
        r.u[0] = 0; r.u[1] = 0; r.u[2] = 0; r.u[3] = 0;
    }
    return r.s;
}

// A-fragment read from the 64x64 f16 activation tile (XOR-swizzled rows)
__device__ __forceinline__ half8 ld_a_h(const unsigned char* hcb, int mt, int kb, int l) {
    const int row = mt * 16 + (l & 15);
    uint32_t byte = (uint32_t)row * 128 + (uint32_t)kb * 64 + (uint32_t)((l >> 4) << 4);
    byte ^= (uint32_t)(row & 7) << 4;
    return *(const half8*)(hcb + byte);
}

__device__ __forceinline__ void st_h(unsigned char* hcb, int row, int col, float v) {
    uint32_t byte = (uint32_t)row * 128 + (uint32_t)col * 2;
    byte ^= (uint32_t)(row & 7) << 4;
    *(uint16_t*)(hcb + byte) = f2h(fmaxf(v, 0.f));
}

#define MFMA(a, b, c) __builtin_amdgcn_mfma_f32_16x16x32_f16((a), (b), (c), 0, 0, 0)

__global__ void __launch_bounds__(256, 3) nerf_fused(
    const float* __restrict__ g_pos,
    const float* __restrict__ g_dir,
    const float* __restrict__ g_tab,
    const float* __restrict__ g_wd1,
    const float* __restrict__ g_bd1,
    const float* __restrict__ g_wd2,
    const float* __restrict__ g_bd2,
    const float* __restrict__ g_wc1,
    const float* __restrict__ g_bc1,
    const float* __restrict__ g_wc2,
    const float* __restrict__ g_bc2,
    const float* __restrict__ g_wc3,
    const float* __restrict__ g_bc3,
    float* __restrict__ g_out)
{
    // per-wave private LDS: [0,8192) activation tile, [8192,12288) xin tile.
    // Tiles are wave-private -> no __syncthreads needed.
    __shared__ __align__(16) unsigned char s_lds[4 * 12288];
    unsigned char* wbase = s_lds + (threadIdx.x >> 6) * 12288;
    unsigned char* hcb  = wbase;
    unsigned char* xinb = wbase + 8192;

    const int l = threadIdx.x & 63;
    const int m_my = l >> 4;      // which 16-row group this thread's point is in
    const int r_my = l & 15;
    const int wpt  = blockIdx.x * 256 + (threadIdx.x & 192); // wave's point base
    const int p    = wpt + l;

    const float px = g_pos[3 * p + 0];
    const float py = g_pos[3 * p + 1];
    const float pz = g_pos[3 * p + 2];
    const float dx = g_dir[3 * p + 0];
    const float dy = g_dir[3 * p + 1];
    const float dz = g_dir[3 * p + 2];

    constexpr float scale[16] = {16.f, 21.f, 27.f, 36.f, 48.f, 64.f, 84.f, 111.f,
                                 147.f, 194.f, 256.f, 337.f, 445.f, 588.f, 776.f, 1024.f};

    // ---------- hash encoding: write enc directly in A-fragment layout ----------
    #pragma unroll
    for (int kb = 0; kb < 4; ++kb) {
        uint32_t w[4];
        #pragma unroll
        for (int l4 = 0; l4 < 4; ++l4) {
            const int lev = kb * 4 + l4;
            const float s = scale[lev];
            const float sx = px * s, sy = py * s, sz = pz * s;
            const float fx = floorf(sx), fy = floorf(sy), fz = floorf(sz);
            const float cx = ceilf(sx),  cy = ceilf(sy),  cz = ceilf(sz);
            const float tx = sx - fx, ty = sy - fy, tz = sz - fz;
            const uint32_t x0 = (uint32_t)fx, x1 = (uint32_t)cx;
            const uint32_t hy0 = (uint32_t)fy * 2654435761u, hy1 = (uint32_t)cy * 2654435761u;
            const uint32_t hz0 = (uint32_t)fz * 805459861u,  hz1 = (uint32_t)cz * 805459861u;
            const uint32_t base = (uint32_t)lev * TBL;
            float e0 = 0.f, e1 = 0.f;
            #pragma unroll
            for (int c = 0; c < 8; ++c) {
                const uint32_t hx = (c & 1) ? x1 : x0;
                const uint32_t hy = (c & 2) ? hy1 : hy0;
                const uint32_t hz = (c & 4) ? hz1 : hz0;
                const uint32_t idx = ((hx ^ hy ^ hz) & TBL_MASK) + base;
                const float2 fv = *reinterpret_cast<const float2*>(g_tab + 2 * (size_t)idx);
                const float wgt = ((c & 1) ? tx : 1.f - tx)
                                * ((c & 2) ? ty : 1.f - ty)
                                * ((c & 4) ? tz : 1.f - tz);
                e0 = fmaf(fv.x, wgt, e0);
                e1 = fmaf(fv.y, wgt, e1);
            }
            w[l4] = pack2(e0, e1);
        }
        *(uint4*)(hcb + m_my * 1024 + (kb * 16 + r_my) * 16) = make_uint4(w[0], w[1], w[2], w[3]);
    }

    // ---------- SH encode -> xin tile k-blocks 2,3 (A-fragment layout) ----------
    {
        const float xx = dx * dx, yy = dy * dy, zz = dz * dz;
        float s[16];
        s[0]  = 0.28209479177387814f;
        s[1]  = 0.4886025119029199f * dy;
        s[2]  = 0.4886025119029199f * dz;
        s[3]  = 0.4886025119029199f * dx;
        s[4]  = 1.0925484305920792f * dx * dy;
        s[5]  = 1.0925484305920792f * dy * dz;
        s[6]  = 0.9461746957575601f * zz - 0.31539156525252f;
        s[7]  = 1.0925484305920792f * dx * dz;
        s[8]  = 0.5462742152960396f * (xx - yy);
        s[9]  = 0.5900435899266435f * dy * (3.f * xx - yy);
        s[10] = 2.890611442640554f * dx * dy * dz;
        s[11] = 0.4570457994644658f * dy * (5.f * zz - 1.f);
        s[12] = 0.3731763325901154f * dz * (5.f * zz - 3.f);
        s[13] = 0.4570457994644658f * dx * (5.f * zz - 1.f);
        s[14] = 1.445305721320277f * dz * (xx - yy);
        s[15] = 0.5900435899266435f * dx * (xx - 3.f * yy);
        *(uint4*)(xinb + m_my * 1024 + (32 + r_my) * 16) =
            make_uint4(pack2(s[0], s[1]), pack2(s[2], s[3]), pack2(s[4], s[5]), pack2(s[6], s[7]));
        *(uint4*)(xinb + m_my * 1024 + (48 + r_my) * 16) =
            make_uint4(pack2(s[8], s[9]), pack2(s[10], s[11]), pack2(s[12], s[13]), pack2(s[14], s[15]));
    }

    const int cl = l & 15;          // output-column lane
    const int rg = (l >> 4) << 2;   // D-fragment row group base

    // ---------- L1: H = relu(ENC @ Wd1 + bd1)  (64x64, K=32) ----------
    {
        f32x4 acc[4][4];
        half8 B[4];
        #pragma unroll
        for (int nt = 0; nt < 4; ++nt) {
            B[nt] = bfrag(g_wd1, 64, 0, nt * 16, l);
            const float b = g_bd1[nt * 16 + cl];
            #pragma unroll
            for (int mt = 0; mt < 4; ++mt) acc[mt][nt] = (f32x4){b, b, b, b};
        }
        #pragma unroll
        for (int mt = 0; mt < 4; ++mt) {
            const half8 A = *(const half8*)(hcb + mt * 1024 + l * 16);
            #pragma unroll
            for (int nt = 0; nt < 4; ++nt) acc[mt][nt] = MFMA(A, B[nt], acc[mt][nt]);
        }
        #pragma unroll
        for (int mt = 0; mt < 4; ++mt)
            #pragma unroll
            for (int nt = 0; nt < 4; ++nt)
                #pragma unroll
                for (int r = 0; r < 4; ++r)
                    st_h(hcb, mt * 16 + rg + r, nt * 16 + cl, acc[mt][nt][r]);
    }

    // ---------- L2: DENS = H @ Wd2 + bd2  (64x16, K=64) -> output + xin kb 0,1 ----------
    {
        const half8 B0 = bfrag(g_wd2, 16, 0,  0, l);
        const half8 B1 = bfrag(g_wd2, 16, 32, 0, l);
        const float b = g_bd2[cl];
        #pragma unroll
        for (int mt = 0; mt < 4; ++mt) {
            f32x4 acc = (f32x4){b, b, b, b};
            acc = MFMA(ld_a_h(hcb, mt, 0, l), B0, acc);
            acc = MFMA(ld_a_h(hcb, mt, 1, l), B1, acc);
            #pragma unroll
            for (int r = 0; r < 4; ++r) {
                const int pt = wpt + mt * 16 + rg + r;
                g_out[(size_t)pt * 16 + cl] = acc[r];
                const uint32_t byte = (uint32_t)mt * 1024
                                    + (uint32_t)(((cl >> 3) * 16 + rg + r) * 16) + (uint32_t)(cl & 7) * 2;
                *(uint16_t*)(xinb + byte) = f2h(acc[r]);
            }
        }
    }

    // ---------- L3: C1 = relu(XIN @ Wc1 + bc1)  (64x64, K=32) ----------
    {
        f32x4 acc[4][4];
        half8 B[4];
        #pragma unroll
        for (int nt = 0; nt < 4; ++nt) {
            B[nt] = bfrag(g_wc1, 64, 0, nt * 16, l);
            const float b = g_bc1[nt * 16 + cl];
            #pragma unroll
            for (int mt = 0; mt < 4; ++mt) acc[mt][nt] = (f32x4){b, b, b, b};
        }
        #pragma unroll
        for (int mt = 0; mt < 4; ++mt) {
            const half8 A = *(const half8*)(xinb + mt * 1024 + l * 16);
            #pragma unroll
            for (int nt = 0; nt < 4; ++nt) acc[mt][nt] = MFMA(A, B[nt], acc[mt][nt]);
        }
        #pragma unroll
        for (int mt = 0; mt < 4; ++mt)
            #pragma unroll
            for (int nt = 0; nt < 4; ++nt)
                #pragma unroll
                for (int r = 0; r < 4; ++r)
                    st_h(hcb, mt * 16 + rg + r, nt * 16 + cl, acc[mt][nt][r]);
    }

    // ---------- L4: C2 = relu(C1 @ Wc2 + bc2)  (64x64, K=64) ----------
    {
        f32x4 acc[4][4];
        #pragma unroll
        for (int nt = 0; nt < 4; ++nt) {
            const float b = g_bc2[nt * 16 + cl];
            #pragma unroll
            for (int mt = 0; mt < 4; ++mt) acc[mt][nt] = (f32x4){b, b, b, b};
        }
        #pragma unroll
        for (int kb = 0; kb < 2; ++kb) {
            half8 A[4];
            #pragma unroll
            for (int mt = 0; mt < 4; ++mt) A[mt] = ld_a_h(hcb, mt, kb, l);
            #pragma unroll
            for (int nt = 0; nt < 4; ++nt) {
                const half8 B = bfrag(g_wc2, 64, kb * 32, nt * 16, l);
                #pragma unroll
                for (int mt = 0; mt < 4; ++mt) acc[mt][nt] = MFMA(A[mt], B, acc[mt][nt]);
            }
        }
        #pragma unroll
        for (int mt = 0; mt < 4; ++mt)
            #pragma unroll
            for (int nt = 0; nt < 4; ++nt)
                #pragma unroll
                for (int r = 0; r < 4; ++r)
                    st_h(hcb, mt * 16 + rg + r, nt * 16 + cl, acc[mt][nt][r]);
    }

    // ---------- L5: color = sigmoid(C2 @ Wc3 + bc3)  (64x3 padded to 16, K=64) ----------
    {
        const half8 B0 = bfrag3(g_wc3, 0, l);
        const half8 B1 = bfrag3(g_wc3, 32, l);
        const float b = (cl < 3) ? g_bc3[cl] : 0.f;
        #pragma unroll
        for (int mt = 0; mt < 4; ++mt) {
            f32x4 acc = (f32x4){b, b, b, b};
            acc = MFMA(ld_a_h(hcb, mt, 0, l), B0, acc);
            acc = MFMA(ld_a_h(hcb, mt, 1, l), B1, acc);
            if (cl < 3) {
                #pragma unroll
                for (int r = 0; r < 4; ++r) {
                    const int pt = wpt + mt * 16 + rg + r;
                    g_out[(size_t)NPTS * 16 + (size_t)pt * 3 + cl] = 1.f / (1.f + expf(-acc[r]));
                }
            }
        }
    }
}

extern "C" void kernel_launch(void* const* d_in, const int* in_sizes, int n_in,
                              void* d_out, int out_size, void* d_ws, size_t ws_size,
                              hipStream_t stream) {
    nerf_fused<<<NPTS / 256, 256, 0, stream>>>(
        (const float*)d_in[0],   // position
        (const float*)d_in[1],   // direction
        (const float*)d_in[2],   // hash_table
        (const float*)d_in[3],   // w_d1
        (const float*)d_in[4],   // b_d1
        (const float*)d_in[5],   // w_d2
        (const float*)d_in[6],   // b_d2
        (const float*)d_in[7],   // w_c1
        (const float*)d_in[8],   // b_c1
        (const float*)d_in[9],   // w_c2
        (const float*)d_in[10],  // b_c2
        (const float*)d_in[11],  // w_c3
        (const float*)d_in[12],  // b_c3
        (float*)d_out);
}

// Round 5
// 171.495 us; speedup vs baseline: 1.9150x; 1.2463x over previous
//
#include <hip/hip_runtime.h>
#include <stdint.h>

#define NPTS 262144
#define TBL 524288u
#define TBL_MASK 524287u

#define WS_TAB_BYTES (16u * 524288u * 4u)          /* 33,554,432 */
#define WS_ENC_OFF   WS_TAB_BYTES
#define WS_ENC_BYTES (16u * (uint32_t)NPTS * 4u)   /* 16,777,216 */
#define WS_NEED      ((size_t)WS_TAB_BYTES + (size_t)WS_ENC_BYTES)

typedef __attribute__((ext_vector_type(8))) _Float16 half8;
typedef __attribute__((ext_vector_type(4))) float f32x4;

__device__ const float d_scale[16] = {16.f, 21.f, 27.f, 36.f, 48.f, 64.f, 84.f, 111.f,
                                      147.f, 194.f, 256.f, 337.f, 445.f, 588.f, 776.f, 1024.f};

__device__ __forceinline__ uint16_t f2h(float f) {
    _Float16 h = (_Float16)f;               // v_cvt_f16_f32, RNE
    return __builtin_bit_cast(uint16_t, h);
}
__device__ __forceinline__ uint32_t pack2(float lo, float hi) {
    return (uint32_t)f2h(lo) | ((uint32_t)f2h(hi) << 16);
}
__device__ __forceinline__ float h2f_lo(uint32_t v) {
    return (float)__builtin_bit_cast(_Float16, (uint16_t)(v & 0xffffu));
}
__device__ __forceinline__ float h2f_hi(uint32_t v) {
    return (float)__builtin_bit_cast(_Float16, (uint16_t)(v >> 16));
}

// B-fragment for 16x16x32 f16 MFMA from row-major [K][N] f32 weights:
// lane l holds B[k = kofs + (l>>4)*8 + j][n = nofs + (l&15)], j = 0..7
__device__ __forceinline__ half8 bfrag(const float* __restrict__ W, int N, int kofs, int nofs, int l) {
    const int k0 = kofs + ((l >> 4) << 3);
    const float* p = W + (size_t)k0 * N + (nofs + (l & 15));
    union { uint32_t u[4]; half8 s; } r;
    r.u[0] = pack2(p[0 * N], p[1 * N]);
    r.u[1] = pack2(p[2 * N], p[3 * N]);
    r.u[2] = pack2(p[4 * N], p[5 * N]);
    r.u[3] = pack2(p[6 * N], p[7 * N]);
    return r.s;
}

// wc3 is [64][3]; pad N to 16 with zeros
__device__ __forceinline__ half8 bfrag3(const float* __restrict__ W, int kofs, int l) {
    const int k0 = kofs + ((l >> 4) << 3);
    const int n = l & 15;
    union { uint32_t u[4]; half8 s; } r;
    if (n < 3) {
        const float* p = W + (size_t)k0 * 3 + n;
        r.u[0] = pack2(p[0],  p[3]);
        r.u[1] = pack2(p[6],  p[9]);
        r.u[2] = pack2(p[12], p[15]);
        r.u[3] = pack2(p[18], p[21]);
    } else {
        r.u[0] = 0; r.u[1] = 0; r.u[2] = 0; r.u[3] = 0;
    }
    return r.s;
}

// A-fragment read from the 64x64 f16 activation tile (XOR-swizzled rows)
__device__ __forceinline__ half8 ld_a_h(const unsigned char* hcb, int mt, int kb, int l) {
    const int row = mt * 16 + (l & 15);
    uint32_t byte = (uint32_t)row * 128 + (uint32_t)kb * 64 + (uint32_t)((l >> 4) << 4);
    byte ^= (uint32_t)(row & 7) << 4;
    return *(const half8*)(hcb + byte);
}

__device__ __forceinline__ void st_h(unsigned char* hcb, int row, int col, float v) {
    uint32_t byte = (uint32_t)row * 128 + (uint32_t)col * 2;
    byte ^= (uint32_t)(row & 7) << 4;
    *(uint16_t*)(hcb + byte) = f2h(fmaxf(v, 0.f));
}

#define MFMA(a, b, c) __builtin_amdgcn_mfma_f32_16x16x32_f16((a), (b), (c), 0, 0, 0)

// ============================ k0: table fp32 -> fp16 ============================
__global__ void __launch_bounds__(256) convert_tab(
    const float4* __restrict__ t, uint4* __restrict__ o, int n4)
{
    const int i = blockIdx.x * 256 + threadIdx.x;
    if (i < n4) {
        const float4 a = t[2 * i];
        const float4 b = t[2 * i + 1];
        o[i] = make_uint4(pack2(a.x, a.y), pack2(a.z, a.w),
                          pack2(b.x, b.y), pack2(b.z, b.w));
    }
}

// ============== k1: level-phased gather (XCD-pinned levels), enc[lev][p] ==============
__global__ void __launch_bounds__(256) gather_enc(
    const float* __restrict__ g_pos,
    const uint32_t* __restrict__ tab16,
    uint32_t* __restrict__ enc)
{
    const int b = blockIdx.x;                       // 16384 blocks
    const int lev = (b & 7) + ((b >> 13) << 3);     // XCD x handles levels x, x+8
    const int p = (((b >> 3) & 1023) << 8) + threadIdx.x;

    const float px = g_pos[3 * p + 0];
    const float py = g_pos[3 * p + 1];
    const float pz = g_pos[3 * p + 2];

    const float s = d_scale[lev];
    const float sx = px * s, sy = py * s, sz = pz * s;
    const float fx = floorf(sx), fy = floorf(sy), fz = floorf(sz);
    const float cx = ceilf(sx),  cy = ceilf(sy),  cz = ceilf(sz);
    const float tx = sx - fx, ty = sy - fy, tz = sz - fz;
    const uint32_t x0 = (uint32_t)fx, x1 = (uint32_t)cx;
    const uint32_t hy0 = (uint32_t)fy * 2654435761u, hy1 = (uint32_t)cy * 2654435761u;
    const uint32_t hz0 = (uint32_t)fz * 805459861u,  hz1 = (uint32_t)cz * 805459861u;

    const uint32_t* t = tab16 + (size_t)lev * TBL;
    float e0 = 0.f, e1 = 0.f;
    #pragma unroll
    for (int c = 0; c < 8; ++c) {
        const uint32_t hx = (c & 1) ? x1 : x0;
        const uint32_t hy = (c & 2) ? hy1 : hy0;
        const uint32_t hz = (c & 4) ? hz1 : hz0;
        const uint32_t idx = (hx ^ hy ^ hz) & TBL_MASK;
        const uint32_t v = t[idx];
        const float wgt = ((c & 1) ? tx : 1.f - tx)
                        * ((c & 2) ? ty : 1.f - ty)
                        * ((c & 4) ? tz : 1.f - tz);
        e0 = fmaf(h2f_lo(v), wgt, e0);
        e1 = fmaf(h2f_hi(v), wgt, e1);
    }
    enc[(size_t)lev * NPTS + p] = pack2(e0, e1);
}

// ============================ k2: MLP (MFMA) ============================
__global__ void __launch_bounds__(256, 3) nerf_mlp(
    const float* __restrict__ g_dir,
    const uint32_t* __restrict__ enc,
    const float* __restrict__ g_wd1,
    const float* __restrict__ g_bd1,
    const float* __restrict__ g_wd2,
    const float* __restrict__ g_bd2,
    const float* __restrict__ g_wc1,
    const float* __restrict__ g_bc1,
    const float* __restrict__ g_wc2,
    const float* __restrict__ g_bc2,
    const float* __restrict__ g_wc3,
    const float* __restrict__ g_bc3,
    float* __restrict__ g_out)
{
    __shared__ __align__(16) unsigned char s_lds[4 * 12288];
    unsigned char* wbase = s_lds + (threadIdx.x >> 6) * 12288;
    unsigned char* hcb  = wbase;
    unsigned char* xinb = wbase + 8192;

    const int l = threadIdx.x & 63;
    const int m_my = l >> 4;
    const int r_my = l & 15;
    const int wpt  = blockIdx.x * 256 + (threadIdx.x & 192);
    const int p    = wpt + l;

    // ---------- enc load -> A-fragment layout in LDS ----------
    #pragma unroll
    for (int kb = 0; kb < 4; ++kb) {
        uint4 w4;
        w4.x = enc[(size_t)(4 * kb + 0) * NPTS + p];
        w4.y = enc[(size_t)(4 * kb + 1) * NPTS + p];
        w4.z = enc[(size_t)(4 * kb + 2) * NPTS + p];
        w4.w = enc[(size_t)(4 * kb + 3) * NPTS + p];
        *(uint4*)(hcb + m_my * 1024 + (kb * 16 + r_my) * 16) = w4;
    }

    const float dx = g_dir[3 * p + 0];
    const float dy = g_dir[3 * p + 1];
    const float dz = g_dir[3 * p + 2];

    // ---------- SH encode -> xin tile k-blocks 2,3 (A-fragment layout) ----------
    {
        const float xx = dx * dx, yy = dy * dy, zz = dz * dz;
        float s[16];
        s[0]  = 0.28209479177387814f;
        s[1]  = 0.4886025119029199f * dy;
        s[2]  = 0.4886025119029199f * dz;
        s[3]  = 0.4886025119029199f * dx;
        s[4]  = 1.0925484305920792f * dx * dy;
        s[5]  = 1.0925484305920792f * dy * dz;
        s[6]  = 0.9461746957575601f * zz - 0.31539156525252f;
        s[7]  = 1.0925484305920792f * dx * dz;
        s[8]  = 0.5462742152960396f * (xx - yy);
        s[9]  = 0.5900435899266435f * dy * (3.f * xx - yy);
        s[10] = 2.890611442640554f * dx * dy * dz;
        s[11] = 0.4570457994644658f * dy * (5.f * zz - 1.f);
        s[12] = 0.3731763325901154f * dz * (5.f * zz - 3.f);
        s[13] = 0.4570457994644658f * dx * (5.f * zz - 1.f);
        s[14] = 1.445305721320277f * dz * (xx - yy);
        s[15] = 0.5900435899266435f * dx * (xx - 3.f * yy);
        *(uint4*)(xinb + m_my * 1024 + (32 + r_my) * 16) =
            make_uint4(pack2(s[0], s[1]), pack2(s[2], s[3]), pack2(s[4], s[5]), pack2(s[6], s[7]));
        *(uint4*)(xinb + m_my * 1024 + (48 + r_my) * 16) =
            make_uint4(pack2(s[8], s[9]), pack2(s[10], s[11]), pack2(s[12], s[13]), pack2(s[14], s[15]));
    }

    const int cl = l & 15;
    const int rg = (l >> 4) << 2;

    // ---------- L1: H = relu(ENC @ Wd1 + bd1)  (64x64, K=32) ----------
    {
        f32x4 acc[4][4];
        half8 B[4];
        #pragma unroll
        for (int nt = 0; nt < 4; ++nt) {
            B[nt] = bfrag(g_wd1, 64, 0, nt * 16, l);
            const float b = g_bd1[nt * 16 + cl];
            #pragma unroll
            for (int mt = 0; mt < 4; ++mt) acc[mt][nt] = (f32x4){b, b, b, b};
        }
        #pragma unroll
        for (int mt = 0; mt < 4; ++mt) {
            const half8 A = *(const half8*)(hcb + mt * 1024 + l * 16);
            #pragma unroll
            for (int nt = 0; nt < 4; ++nt) acc[mt][nt] = MFMA(A, B[nt], acc[mt][nt]);
        }
        #pragma unroll
        for (int mt = 0; mt < 4; ++mt)
            #pragma unroll
            for (int nt = 0; nt < 4; ++nt)
                #pragma unroll
                for (int r = 0; r < 4; ++r)
                    st_h(hcb, mt * 16 + rg + r, nt * 16 + cl, acc[mt][nt][r]);
    }

    // ---------- L2: DENS = H @ Wd2 + bd2  (64x16, K=64) -> output + xin kb 0,1 ----------
    {
        const half8 B0 = bfrag(g_wd2, 16, 0,  0, l);
        const half8 B1 = bfrag(g_wd2, 16, 32, 0, l);
        const float b = g_bd2[cl];
        #pragma unroll
        for (int mt = 0; mt < 4; ++mt) {
            f32x4 acc = (f32x4){b, b, b, b};
            acc = MFMA(ld_a_h(hcb, mt, 0, l), B0, acc);
            acc = MFMA(ld_a_h(hcb, mt, 1, l), B1, acc);
            #pragma unroll
            for (int r = 0; r < 4; ++r) {
                const int pt = wpt + mt * 16 + rg + r;
                g_out[(size_t)pt * 16 + cl] = acc[r];
                const uint32_t byte = (uint32_t)mt * 1024
                                    + (uint32_t)(((cl >> 3) * 16 + rg + r) * 16) + (uint32_t)(cl & 7) * 2;
                *(uint16_t*)(xinb + byte) = f2h(acc[r]);
            }
        }
    }

    // ---------- L3: C1 = relu(XIN @ Wc1 + bc1)  (64x64, K=32) ----------
    {
        f32x4 acc[4][4];
        half8 B[4];
        #pragma unroll
        for (int nt = 0; nt < 4; ++nt) {
            B[nt] = bfrag(g_wc1, 64, 0, nt * 16, l);
            const float b = g_bc1[nt * 16 + cl];
            #pragma unroll
            for (int mt = 0; mt < 4; ++mt) acc[mt][nt] = (f32x4){b, b, b, b};
        }
        #pragma unroll
        for (int mt = 0; mt < 4; ++mt) {
            const half8 A = *(const half8*)(xinb + mt * 1024 + l * 16);
            #pragma unroll
            for (int nt = 0; nt < 4; ++nt) acc[mt][nt] = MFMA(A, B[nt], acc[mt][nt]);
        }
        #pragma unroll
        for (int mt = 0; mt < 4; ++mt)
            #pragma unroll
            for (int nt = 0; nt < 4; ++nt)
                #pragma unroll
                for (int r = 0; r < 4; ++r)
                    st_h(hcb, mt * 16 + rg + r, nt * 16 + cl, acc[mt][nt][r]);
    }

    // ---------- L4: C2 = relu(C1 @ Wc2 + bc2)  (64x64, K=64) ----------
    {
        f32x4 acc[4][4];
        #pragma unroll
        for (int nt = 0; nt < 4; ++nt) {
            const float b = g_bc2[nt * 16 + cl];
            #pragma unroll
            for (int mt = 0; mt < 4; ++mt) acc[mt][nt] = (f32x4){b, b, b, b};
        }
        #pragma unroll
        for (int kb = 0; kb < 2; ++kb) {
            half8 A[4];
            #pragma unroll
            for (int mt = 0; mt < 4; ++mt) A[mt] = ld_a_h(hcb, mt, kb, l);
            #pragma unroll
            for (int nt = 0; nt < 4; ++nt) {
                const half8 B = bfrag(g_wc2, 64, kb * 32, nt * 16, l);
                #pragma unroll
                for (int mt = 0; mt < 4; ++mt) acc[mt][nt] = MFMA(A[mt], B, acc[mt][nt]);
            }
        }
        #pragma unroll
        for (int mt = 0; mt < 4; ++mt)
            #pragma unroll
            for (int nt = 0; nt < 4; ++nt)
                #pragma unroll
                for (int r = 0; r < 4; ++r)
                    st_h(hcb, mt * 16 + rg + r, nt * 16 + cl, acc[mt][nt][r]);
    }

    // ---------- L5: color = sigmoid(C2 @ Wc3 + bc3)  (64x3 padded to 16, K=64) ----------
    {
        const half8 B0 = bfrag3(g_wc3, 0, l);
        const half8 B1 = bfrag3(g_wc3, 32, l);
        const float b = (cl < 3) ? g_bc3[cl] : 0.f;
        #pragma unroll
        for (int mt = 0; mt < 4; ++mt) {
            f32x4 acc = (f32x4){b, b, b, b};
            acc = MFMA(ld_a_h(hcb, mt, 0, l), B0, acc);
            acc = MFMA(ld_a_h(hcb, mt, 1, l), B1, acc);
            if (cl < 3) {
                #pragma unroll
                for (int r = 0; r < 4; ++r) {
                    const int pt = wpt + mt * 16 + rg + r;
                    g_out[(size_t)NPTS * 16 + (size_t)pt * 3 + cl] = 1.f / (1.f + expf(-acc[r]));
                }
            }
        }
    }
}

// ================== fallback: round-4 fused kernel (ws too small) ==================
__global__ void __launch_bounds__(256, 3) nerf_fused(
    const float* __restrict__ g_pos,
    const float* __restrict__ g_dir,
    const float* __restrict__ g_tab,
    const float* __restrict__ g_wd1,
    const float* __restrict__ g_bd1,
    const float* __restrict__ g_wd2,
    const float* __restrict__ g_bd2,
    const float* __restrict__ g_wc1,
    const float* __restrict__ g_bc1,
    const float* __restrict__ g_wc2,
    const float* __restrict__ g_bc2,
    const float* __restrict__ g_wc3,
    const float* __restrict__ g_bc3,
    float* __restrict__ g_out)
{
    __shared__ __align__(16) unsigned char s_lds[4 * 12288];
    unsigned char* wbase = s_lds + (threadIdx.x >> 6) * 12288;
    unsigned char* hcb  = wbase;
    unsigned char* xinb = wbase + 8192;

    const int l = threadIdx.x & 63;
    const int m_my = l >> 4;
    const int r_my = l & 15;
    const int wpt  = blockIdx.x * 256 + (threadIdx.x & 192);
    const int p    = wpt + l;

    const float px = g_pos[3 * p + 0];
    const float py = g_pos[3 * p + 1];
    const float pz = g_pos[3 * p + 2];
    const float dx = g_dir[3 * p + 0];
    const float dy = g_dir[3 * p + 1];
    const float dz = g_dir[3 * p + 2];

    constexpr float scale[16] = {16.f, 21.f, 27.f, 36.f, 48.f, 64.f, 84.f, 111.f,
                                 147.f, 194.f, 256.f, 337.f, 445.f, 588.f, 776.f, 1024.f};

    #pragma unroll
    for (int kb = 0; kb < 4; ++kb) {
        uint32_t w[4];
        #pragma unroll
        for (int l4 = 0; l4 < 4; ++l4) {
            const int lev = kb * 4 + l4;
            const float s = scale[lev];
            const float sx = px * s, sy = py * s, sz = pz * s;
            const float fx = floorf(sx), fy = floorf(sy), fz = floorf(sz);
            const float cx = ceilf(sx),  cy = ceilf(sy),  cz = ceilf(sz);
            const float tx = sx - fx, ty = sy - fy, tz = sz - fz;
            const uint32_t x0 = (uint32_t)fx, x1 = (uint32_t)cx;
            const uint32_t hy0 = (uint32_t)fy * 2654435761u, hy1 = (uint32_t)cy * 2654435761u;
            const uint32_t hz0 = (uint32_t)fz * 805459861u,  hz1 = (uint32_t)cz * 805459861u;
            const uint32_t base = (uint32_t)lev * TBL;
            float e0 = 0.f, e1 = 0.f;
            #pragma unroll
            for (int c = 0; c < 8; ++c) {
                const uint32_t hx = (c & 1) ? x1 : x0;
                const uint32_t hy = (c & 2) ? hy1 : hy0;
                const uint32_t hz = (c & 4) ? hz1 : hz0;
                const uint32_t idx = ((hx ^ hy ^ hz) & TBL_MASK) + base;
                const float2 fv = *reinterpret_cast<const float2*>(g_tab + 2 * (size_t)idx);
                const float wgt = ((c & 1) ? tx : 1.f - tx)
                                * ((c & 2) ? ty : 1.f - ty)
                                * ((c & 4) ? tz : 1.f - tz);
                e0 = fmaf(fv.x, wgt, e0);
                e1 = fmaf(fv.y, wgt, e1);
            }
            w[l4] = pack2(e0, e1);
        }
        *(uint4*)(hcb + m_my * 1024 + (kb * 16 + r_my) * 16) = make_uint4(w[0], w[1], w[2], w[3]);
    }

    {
        const float xx = dx * dx, yy = dy * dy, zz = dz * dz;
        float s[16];
        s[0]  = 0.28209479177387814f;
        s[1]  = 0.4886025119029199f * dy;
        s[2]  = 0.4886025119029199f * dz;
        s[3]  = 0.4886025119029199f * dx;
        s[4]  = 1.0925484305920792f * dx * dy;
        s[5]  = 1.0925484305920792f * dy * dz;
        s[6]  = 0.9461746957575601f * zz - 0.31539156525252f;
        s[7]  = 1.0925484305920792f * dx * dz;
        s[8]  = 0.5462742152960396f * (xx - yy);
        s[9]  = 0.5900435899266435f * dy * (3.f * xx - yy);
        s[10] = 2.890611442640554f * dx * dy * dz;
        s[11] = 0.4570457994644658f * dy * (5.f * zz - 1.f);
        s[12] = 0.3731763325901154f * dz * (5.f * zz - 3.f);
        s[13] = 0.4570457994644658f * dx * (5.f * zz - 1.f);
        s[14] = 1.445305721320277f * dz * (xx - yy);
        s[15] = 0.5900435899266435f * dx * (xx - 3.f * yy);
        *(uint4*)(xinb + m_my * 1024 + (32 + r_my) * 16) =
            make_uint4(pack2(s[0], s[1]), pack2(s[2], s[3]), pack2(s[4], s[5]), pack2(s[6], s[7]));
        *(uint4*)(xinb + m_my * 1024 + (48 + r_my) * 16) =
            make_uint4(pack2(s[8], s[9]), pack2(s[10], s[11]), pack2(s[12], s[13]), pack2(s[14], s[15]));
    }

    const int cl = l & 15;
    const int rg = (l >> 4) << 2;

    {
        f32x4 acc[4][4];
        half8 B[4];
        #pragma unroll
        for (int nt = 0; nt < 4; ++nt) {
            B[nt] = bfrag(g_wd1, 64, 0, nt * 16, l);
            const float b = g_bd1[nt * 16 + cl];
            #pragma unroll
            for (int mt = 0; mt < 4; ++mt) acc[mt][nt] = (f32x4){b, b, b, b};
        }
        #pragma unroll
        for (int mt = 0; mt < 4; ++mt) {
            const half8 A = *(const half8*)(hcb + mt * 1024 + l * 16);
            #pragma unroll
            for (int nt = 0; nt < 4; ++nt) acc[mt][nt] = MFMA(A, B[nt], acc[mt][nt]);
        }
        #pragma unroll
        for (int mt = 0; mt < 4; ++mt)
            #pragma unroll
            for (int nt = 0; nt < 4; ++nt)
                #pragma unroll
                for (int r = 0; r < 4; ++r)
                    st_h(hcb, mt * 16 + rg + r, nt * 16 + cl, acc[mt][nt][r]);
    }

    {
        const half8 B0 = bfrag(g_wd2, 16, 0,  0, l);
        const half8 B1 = bfrag(g_wd2, 16, 32, 0, l);
        const float b = g_bd2[cl];
        #pragma unroll
        for (int mt = 0; mt < 4; ++mt) {
            f32x4 acc = (f32x4){b, b, b, b};
            acc = MFMA(ld_a_h(hcb, mt, 0, l), B0, acc);
            acc = MFMA(ld_a_h(hcb, mt, 1, l), B1, acc);
            #pragma unroll
            for (int r = 0; r < 4; ++r) {
                const int pt = wpt + mt * 16 + rg + r;
                g_out[(size_t)pt * 16 + cl] = acc[r];
                const uint32_t byte = (uint32_t)mt * 1024
                                    + (uint32_t)(((cl >> 3) * 16 + rg + r) * 16) + (uint32_t)(cl & 7) * 2;
                *(uint16_t*)(xinb + byte) = f2h(acc[r]);
            }
        }
    }

    {
        f32x4 acc[4][4];
        half8 B[4];
        #pragma unroll
        for (int nt = 0; nt < 4; ++nt) {
            B[nt] = bfrag(g_wc1, 64, 0, nt * 16, l);
            const float b = g_bc1[nt * 16 + cl];
            #pragma unroll
            for (int mt = 0; mt < 4; ++mt) acc[mt][nt] = (f32x4){b, b, b, b};
        }
        #pragma unroll
        for (int mt = 0; mt < 4; ++mt) {
            const half8 A = *(const half8*)(xinb + mt * 1024 + l * 16);
            #pragma unroll
            for (int nt = 0; nt < 4; ++nt) acc[mt][nt] = MFMA(A, B[nt], acc[mt][nt]);
        }
        #pragma unroll
        for (int mt = 0; mt < 4; ++mt)
            #pragma unroll
            for (int nt = 0; nt < 4; ++nt)
                #pragma unroll
                for (int r = 0; r < 4; ++r)
                    st_h(hcb, mt * 16 + rg + r, nt * 16 + cl, acc[mt][nt][r]);
    }

    {
        f32x4 acc[4][4];
        #pragma unroll
        for (int nt = 0; nt < 4; ++nt) {
            const float b = g_bc2[nt * 16 + cl];
            #pragma unroll
            for (int mt = 0; mt < 4; ++mt) acc[mt][nt] = (f32x4){b, b, b, b};
        }
        #pragma unroll
        for (int kb = 0; kb < 2; ++kb) {
            half8 A[4];
            #pragma unroll
            for (int mt = 0; mt < 4; ++mt) A[mt] = ld_a_h(hcb, mt, kb, l);
            #pragma unroll
            for (int nt = 0; nt < 4; ++nt) {
                const half8 B = bfrag(g_wc2, 64, kb * 32, nt * 16, l);
                #pragma unroll
                for (int mt = 0; mt < 4; ++mt) acc[mt][nt] = MFMA(A[mt], B, acc[mt][nt]);
            }
        }
        #pragma unroll
        for (int mt = 0; mt < 4; ++mt)
            #pragma unroll
            for (int nt = 0; nt < 4; ++nt)
                #pragma unroll
                for (int r = 0; r < 4; ++r)
                    st_h(hcb, mt * 16 + rg + r, nt * 16 + cl, acc[mt][nt][r]);
    }

    {
        const half8 B0 = bfrag3(g_wc3, 0, l);
        const half8 B1 = bfrag3(g_wc3, 32, l);
        const float b = (cl < 3) ? g_bc3[cl] : 0.f;
        #pragma unroll
        for (int mt = 0; mt < 4; ++mt) {
            f32x4 acc = (f32x4){b, b, b, b};
            acc = MFMA(ld_a_h(hcb, mt, 0, l), B0, acc);
            acc = MFMA(ld_a_h(hcb, mt, 1, l), B1, acc);
            if (cl < 3) {
                #pragma unroll
                for (int r = 0; r < 4; ++r) {
                    const int pt = wpt + mt * 16 + rg + r;
                    g_out[(size_t)NPTS * 16 + (size_t)pt * 3 + cl] = 1.f / (1.f + expf(-acc[r]));
                }
            }
        }
    }
}

extern "C" void kernel_launch(void* const* d_in, const int* in_sizes, int n_in,
                              void* d_out, int out_size, void* d_ws, size_t ws_size,
                              hipStream_t stream) {
    if (ws_size >= WS_NEED) {
        uint32_t* tab16 = (uint32_t*)d_ws;
        uint32_t* enc   = (uint32_t*)((char*)d_ws + WS_ENC_OFF);
        convert_tab<<<8192, 256, 0, stream>>>(
            (const float4*)d_in[2], (uint4*)tab16, 2097152);
        gather_enc<<<16384, 256, 0, stream>>>(
            (const float*)d_in[0], tab16, enc);
        nerf_mlp<<<NPTS / 256, 256, 0, stream>>>(
            (const float*)d_in[1], enc,
            (const float*)d_in[3], (const float*)d_in[4],
            (const float*)d_in[5], (const float*)d_in[6],
            (const float*)d_in[7], (const float*)d_in[8],
            (const float*)d_in[9], (const float*)d_in[10],
            (const float*)d_in[11], (const float*)d_in[12],
            (float*)d_out);
    } else {
        nerf_fused<<<NPTS / 256, 256, 0, stream>>>(
            (const float*)d_in[0], (const float*)d_in[1], (const float*)d_in[2],
            (const float*)d_in[3], (const float*)d_in[4],
            (const float*)d_in[5], (const float*)d_in[6],
            (const float*)d_in[7], (const float*)d_in[8],
            (const float*)d_in[9], (const float*)d_in[10],
            (const float*)d_in[11], (const float*)d_in[12],
            (float*)d_out);
    }
}

// Round 6
// 159.495 us; speedup vs baseline: 2.0590x; 1.0752x over previous
//
#include <hip/hip_runtime.h>
#include <stdint.h>

#define NPTS 262144
#define TBL 524288u
#define TBL_MASK 524287u

#define WS_TAB_BYTES (16u * 524288u * 4u)          /* 33,554,432 */
#define WS_ENC_OFF   WS_TAB_BYTES
#define WS_ENC_BYTES (16u * (uint32_t)NPTS * 4u)   /* 16,777,216 */
#define WS_NEED      ((size_t)WS_TAB_BYTES + (size_t)WS_ENC_BYTES)

typedef __attribute__((ext_vector_type(8))) _Float16 half8;
typedef __attribute__((ext_vector_type(4))) float f32x4;

__device__ const float d_scale[16] = {16.f, 21.f, 27.f, 36.f, 48.f, 64.f, 84.f, 111.f,
                                      147.f, 194.f, 256.f, 337.f, 445.f, 588.f, 776.f, 1024.f};

__device__ __forceinline__ uint16_t f2h(float f) {
    _Float16 h = (_Float16)f;               // v_cvt_f16_f32, RNE
    return __builtin_bit_cast(uint16_t, h);
}
__device__ __forceinline__ uint32_t pack2(float lo, float hi) {
    return (uint32_t)f2h(lo) | ((uint32_t)f2h(hi) << 16);
}
__device__ __forceinline__ float h2f_lo(uint32_t v) {
    return (float)__builtin_bit_cast(_Float16, (uint16_t)(v & 0xffffu));
}
__device__ __forceinline__ float h2f_hi(uint32_t v) {
    return (float)__builtin_bit_cast(_Float16, (uint16_t)(v >> 16));
}

// B-fragment for 16x16x32 f16 MFMA from row-major [K][N] f32 weights:
// lane l holds B[k = kofs + (l>>4)*8 + j][n = nofs + (l&15)], j = 0..7
__device__ __forceinline__ half8 bfrag(const float* __restrict__ W, int N, int kofs, int nofs, int l) {
    const int k0 = kofs + ((l >> 4) << 3);
    const float* p = W + (size_t)k0 * N + (nofs + (l & 15));
    union { uint32_t u[4]; half8 s; } r;
    r.u[0] = pack2(p[0 * N], p[1 * N]);
    r.u[1] = pack2(p[2 * N], p[3 * N]);
    r.u[2] = pack2(p[4 * N], p[5 * N]);
    r.u[3] = pack2(p[6 * N], p[7 * N]);
    return r.s;
}

// wc3 is [64][3]; pad N to 16 with zeros
__device__ __forceinline__ half8 bfrag3(const float* __restrict__ W, int kofs, int l) {
    const int k0 = kofs + ((l >> 4) << 3);
    const int n = l & 15;
    union { uint32_t u[4]; half8 s; } r;
    if (n < 3) {
        const float* p = W + (size_t)k0 * 3 + n;
        r.u[0] = pack2(p[0],  p[3]);
        r.u[1] = pack2(p[6],  p[9]);
        r.u[2] = pack2(p[12], p[15]);
        r.u[3] = pack2(p[18], p[21]);
    } else {
        r.u[0] = 0; r.u[1] = 0; r.u[2] = 0; r.u[3] = 0;
    }
    return r.s;
}

// A-fragment read from the 64x64 f16 activation tile (XOR-swizzled rows)
__device__ __forceinline__ half8 ld_a_h(const unsigned char* hcb, int mt, int kb, int l) {
    const int row = mt * 16 + (l & 15);
    uint32_t byte = (uint32_t)row * 128 + (uint32_t)kb * 64 + (uint32_t)((l >> 4) << 4);
    byte ^= (uint32_t)(row & 7) << 4;
    return *(const half8*)(hcb + byte);
}

__device__ __forceinline__ void st_h(unsigned char* hcb, int row, int col, float v) {
    uint32_t byte = (uint32_t)row * 128 + (uint32_t)col * 2;
    byte ^= (uint32_t)(row & 7) << 4;
    *(uint16_t*)(hcb + byte) = f2h(fmaxf(v, 0.f));
}

#define MFMA(a, b, c) __builtin_amdgcn_mfma_f32_16x16x32_f16((a), (b), (c), 0, 0, 0)

// ============================ k0: table fp32 -> fp16 ============================
__global__ void __launch_bounds__(256) convert_tab(
    const float4* __restrict__ t, uint4* __restrict__ o, int n4)
{
    const int i = blockIdx.x * 256 + threadIdx.x;
    if (i < n4) {
        const float4 a = t[2 * i];
        const float4 b = t[2 * i + 1];
        o[i] = make_uint4(pack2(a.x, a.y), pack2(a.z, a.w),
                          pack2(b.x, b.y), pack2(b.z, b.w));
    }
}

// ============== k1: level-phased gather (XCD-pinned levels), enc[lev][p] ==============
// x-pair trick: hash uses PRIMES[0]==1, so for even x0 the x-floor/x-ceil corners
// are the aligned uint32 pair {idx0&~1, idx0|1} -> one 8B load serves both.
__global__ void __launch_bounds__(256) gather_enc(
    const float* __restrict__ g_pos,
    const uint32_t* __restrict__ tab16,
    uint32_t* __restrict__ enc)
{
    const int b = blockIdx.x;                       // 16384 blocks
    const int x8 = b & 7;                           // XCD hint
    const int lev = (b >> 13) ? (15 - x8) : x8;     // XCD x: levels x and 15-x
    const int p = (((b >> 3) & 1023) << 8) + threadIdx.x;

    const float px = g_pos[3 * p + 0];
    const float py = g_pos[3 * p + 1];
    const float pz = g_pos[3 * p + 2];

    const float s = d_scale[lev];
    const float sx = px * s, sy = py * s, sz = pz * s;
    const float fx = floorf(sx), fy = floorf(sy), fz = floorf(sz);
    const float cx = ceilf(sx),  cy = ceilf(sy),  cz = ceilf(sz);
    const float tx = sx - fx, ty = sy - fy, tz = sz - fz;
    const uint32_t x0 = (uint32_t)fx, x1 = (uint32_t)cx;
    const uint32_t hy0 = (uint32_t)fy * 2654435761u, hy1 = (uint32_t)cy * 2654435761u;
    const uint32_t hz0 = (uint32_t)fz * 805459861u,  hz1 = (uint32_t)cz * 805459861u;
    const bool xodd = (x0 & 1u) != 0u;

    const uint32_t* t = tab16 + (size_t)lev * TBL;
    float e0 = 0.f, e1 = 0.f;
    #pragma unroll
    for (int cp = 0; cp < 4; ++cp) {                // corner pair: (x-floor, x-ceil)
        const uint32_t hyz = ((cp & 1) ? hy1 : hy0) ^ ((cp & 2) ? hz1 : hz0);
        const uint32_t idx0 = (x0 ^ hyz) & TBL_MASK;
        const uint32_t idx1 = (x1 ^ hyz) & TBL_MASK;
        const uint2 v2 = *reinterpret_cast<const uint2*>(t + (idx0 & ~1u));
        const bool lo = (idx0 & 1u) == 0u;
        const uint32_t v0 = lo ? v2.x : v2.y;       // always correct (idx0 in pair)
        uint32_t v1 = lo ? v2.y : v2.x;             // correct iff x0 even (else w1==0 or fixup)
        if (xodd) v1 = t[idx1];
        const float wyz = ((cp & 1) ? ty : 1.f - ty) * ((cp & 2) ? tz : 1.f - tz);
        const float w0 = (1.f - tx) * wyz;
        const float w1 = tx * wyz;
        e0 = fmaf(h2f_lo(v0), w0, fmaf(h2f_lo(v1), w1, e0));
        e1 = fmaf(h2f_hi(v0), w0, fmaf(h2f_hi(v1), w1, e1));
    }
    enc[(size_t)lev * NPTS + p] = pack2(e0, e1);
}

// ============================ k2: MLP (MFMA) ============================
__global__ void __launch_bounds__(256, 3) nerf_mlp(
    const float* __restrict__ g_dir,
    const uint32_t* __restrict__ enc,
    const float* __restrict__ g_wd1,
    const float* __restrict__ g_bd1,
    const float* __restrict__ g_wd2,
    const float* __restrict__ g_bd2,
    const float* __restrict__ g_wc1,
    const float* __restrict__ g_bc1,
    const float* __restrict__ g_wc2,
    const float* __restrict__ g_bc2,
    const float* __restrict__ g_wc3,
    const float* __restrict__ g_bc3,
    float* __restrict__ g_out)
{
    __shared__ __align__(16) unsigned char s_lds[4 * 12288];
    unsigned char* wbase = s_lds + (threadIdx.x >> 6) * 12288;
    unsigned char* hcb  = wbase;
    unsigned char* xinb = wbase + 8192;

    const int l = threadIdx.x & 63;
    const int m_my = l >> 4;
    const int r_my = l & 15;
    const int wpt  = blockIdx.x * 256 + (threadIdx.x & 192);
    const int p    = wpt + l;

    // ---------- enc load -> A-fragment layout in LDS ----------
    #pragma unroll
    for (int kb = 0; kb < 4; ++kb) {
        uint4 w4;
        w4.x = enc[(size_t)(4 * kb + 0) * NPTS + p];
        w4.y = enc[(size_t)(4 * kb + 1) * NPTS + p];
        w4.z = enc[(size_t)(4 * kb + 2) * NPTS + p];
        w4.w = enc[(size_t)(4 * kb + 3) * NPTS + p];
        *(uint4*)(hcb + m_my * 1024 + (kb * 16 + r_my) * 16) = w4;
    }

    const float dx = g_dir[3 * p + 0];
    const float dy = g_dir[3 * p + 1];
    const float dz = g_dir[3 * p + 2];

    // ---------- SH encode -> xin tile k-blocks 2,3 (A-fragment layout) ----------
    {
        const float xx = dx * dx, yy = dy * dy, zz = dz * dz;
        float s[16];
        s[0]  = 0.28209479177387814f;
        s[1]  = 0.4886025119029199f * dy;
        s[2]  = 0.4886025119029199f * dz;
        s[3]  = 0.4886025119029199f * dx;
        s[4]  = 1.0925484305920792f * dx * dy;
        s[5]  = 1.0925484305920792f * dy * dz;
        s[6]  = 0.9461746957575601f * zz - 0.31539156525252f;
        s[7]  = 1.0925484305920792f * dx * dz;
        s[8]  = 0.5462742152960396f * (xx - yy);
        s[9]  = 0.5900435899266435f * dy * (3.f * xx - yy);
        s[10] = 2.890611442640554f * dx * dy * dz;
        s[11] = 0.4570457994644658f * dy * (5.f * zz - 1.f);
        s[12] = 0.3731763325901154f * dz * (5.f * zz - 3.f);
        s[13] = 0.4570457994644658f * dx * (5.f * zz - 1.f);
        s[14] = 1.445305721320277f * dz * (xx - yy);
        s[15] = 0.5900435899266435f * dx * (xx - 3.f * yy);
        *(uint4*)(xinb + m_my * 1024 + (32 + r_my) * 16) =
            make_uint4(pack2(s[0], s[1]), pack2(s[2], s[3]), pack2(s[4], s[5]), pack2(s[6], s[7]));
        *(uint4*)(xinb + m_my * 1024 + (48 + r_my) * 16) =
            make_uint4(pack2(s[8], s[9]), pack2(s[10], s[11]), pack2(s[12], s[13]), pack2(s[14], s[15]));
    }

    const int cl = l & 15;
    const int rg = (l >> 4) << 2;

    // ---------- L1: H = relu(ENC @ Wd1 + bd1)  (64x64, K=32) ----------
    {
        f32x4 acc[4][4];
        half8 B[4];
        #pragma unroll
        for (int nt = 0; nt < 4; ++nt) {
            B[nt] = bfrag(g_wd1, 64, 0, nt * 16, l);
            const float b = g_bd1[nt * 16 + cl];
            #pragma unroll
            for (int mt = 0; mt < 4; ++mt) acc[mt][nt] = (f32x4){b, b, b, b};
        }
        #pragma unroll
        for (int mt = 0; mt < 4; ++mt) {
            const half8 A = *(const half8*)(hcb + mt * 1024 + l * 16);
            #pragma unroll
            for (int nt = 0; nt < 4; ++nt) acc[mt][nt] = MFMA(A, B[nt], acc[mt][nt]);
        }
        #pragma unroll
        for (int mt = 0; mt < 4; ++mt)
            #pragma unroll
            for (int nt = 0; nt < 4; ++nt)
                #pragma unroll
                for (int r = 0; r < 4; ++r)
                    st_h(hcb, mt * 16 + rg + r, nt * 16 + cl, acc[mt][nt][r]);
    }

    // ---------- L2: DENS = H @ Wd2 + bd2  (64x16, K=64) -> output + xin kb 0,1 ----------
    {
        const half8 B0 = bfrag(g_wd2, 16, 0,  0, l);
        const half8 B1 = bfrag(g_wd2, 16, 32, 0, l);
        const float b = g_bd2[cl];
        #pragma unroll
        for (int mt = 0; mt < 4; ++mt) {
            f32x4 acc = (f32x4){b, b, b, b};
            acc = MFMA(ld_a_h(hcb, mt, 0, l), B0, acc);
            acc = MFMA(ld_a_h(hcb, mt, 1, l), B1, acc);
            #pragma unroll
            for (int r = 0; r < 4; ++r) {
                const int pt = wpt + mt * 16 + rg + r;
                g_out[(size_t)pt * 16 + cl] = acc[r];
                const uint32_t byte = (uint32_t)mt * 1024
                                    + (uint32_t)(((cl >> 3) * 16 + rg + r) * 16) + (uint32_t)(cl & 7) * 2;
                *(uint16_t*)(xinb + byte) = f2h(acc[r]);
            }
        }
    }

    // ---------- L3: C1 = relu(XIN @ Wc1 + bc1)  (64x64, K=32) ----------
    {
        f32x4 acc[4][4];
        half8 B[4];
        #pragma unroll
        for (int nt = 0; nt < 4; ++nt) {
            B[nt] = bfrag(g_wc1, 64, 0, nt * 16, l);
            const float b = g_bc1[nt * 16 + cl];
            #pragma unroll
            for (int mt = 0; mt < 4; ++mt) acc[mt][nt] = (f32x4){b, b, b, b};
        }
        #pragma unroll
        for (int mt = 0; mt < 4; ++mt) {
            const half8 A = *(const half8*)(xinb + mt * 1024 + l * 16);
            #pragma unroll
            for (int nt = 0; nt < 4; ++nt) acc[mt][nt] = MFMA(A, B[nt], acc[mt][nt]);
        }
        #pragma unroll
        for (int mt = 0; mt < 4; ++mt)
            #pragma unroll
            for (int nt = 0; nt < 4; ++nt)
                #pragma unroll
                for (int r = 0; r < 4; ++r)
                    st_h(hcb, mt * 16 + rg + r, nt * 16 + cl, acc[mt][nt][r]);
    }

    // ---------- L4: C2 = relu(C1 @ Wc2 + bc2)  (64x64, K=64) ----------
    {
        f32x4 acc[4][4];
        #pragma unroll
        for (int nt = 0; nt < 4; ++nt) {
            const float b = g_bc2[nt * 16 + cl];
            #pragma unroll
            for (int mt = 0; mt < 4; ++mt) acc[mt][nt] = (f32x4){b, b, b, b};
        }
        #pragma unroll
        for (int kb = 0; kb < 2; ++kb) {
            half8 A[4];
            #pragma unroll
            for (int mt = 0; mt < 4; ++mt) A[mt] = ld_a_h(hcb, mt, kb, l);
            #pragma unroll
            for (int nt = 0; nt < 4; ++nt) {
                const half8 B = bfrag(g_wc2, 64, kb * 32, nt * 16, l);
                #pragma unroll
                for (int mt = 0; mt < 4; ++mt) acc[mt][nt] = MFMA(A[mt], B, acc[mt][nt]);
            }
        }
        #pragma unroll
        for (int mt = 0; mt < 4; ++mt)
            #pragma unroll
            for (int nt = 0; nt < 4; ++nt)
                #pragma unroll
                for (int r = 0; r < 4; ++r)
                    st_h(hcb, mt * 16 + rg + r, nt * 16 + cl, acc[mt][nt][r]);
    }

    // ---------- L5: color = sigmoid(C2 @ Wc3 + bc3)  (64x3 padded to 16, K=64) ----------
    {
        const half8 B0 = bfrag3(g_wc3, 0, l);
        const half8 B1 = bfrag3(g_wc3, 32, l);
        const float b = (cl < 3) ? g_bc3[cl] : 0.f;
        #pragma unroll
        for (int mt = 0; mt < 4; ++mt) {
            f32x4 acc = (f32x4){b, b, b, b};
            acc = MFMA(ld_a_h(hcb, mt, 0, l), B0, acc);
            acc = MFMA(ld_a_h(hcb, mt, 1, l), B1, acc);
            if (cl < 3) {
                #pragma unroll
                for (int r = 0; r < 4; ++r) {
                    const int pt = wpt + mt * 16 + rg + r;
                    g_out[(size_t)NPTS * 16 + (size_t)pt * 3 + cl] = 1.f / (1.f + expf(-acc[r]));
                }
            }
        }
    }
}

// ================== fallback: round-4 fused kernel (ws too small) ==================
__global__ void __launch_bounds__(256, 3) nerf_fused(
    const float* __restrict__ g_pos,
    const float* __restrict__ g_dir,
    const float* __restrict__ g_tab,
    const float* __restrict__ g_wd1,
    const float* __restrict__ g_bd1,
    const float* __restrict__ g_wd2,
    const float* __restrict__ g_bd2,
    const float* __restrict__ g_wc1,
    const float* __restrict__ g_bc1,
    const float* __restrict__ g_wc2,
    const float* __restrict__ g_bc2,
    const float* __restrict__ g_wc3,
    const float* __restrict__ g_bc3,
    float* __restrict__ g_out)
{
    __shared__ __align__(16) unsigned char s_lds[4 * 12288];
    unsigned char* wbase = s_lds + (threadIdx.x >> 6) * 12288;
    unsigned char* hcb  = wbase;
    unsigned char* xinb = wbase + 8192;

    const int l = threadIdx.x & 63;
    const int m_my = l >> 4;
    const int r_my = l & 15;
    const int wpt  = blockIdx.x * 256 + (threadIdx.x & 192);
    const int p    = wpt + l;

    const float px = g_pos[3 * p + 0];
    const float py = g_pos[3 * p + 1];
    const float pz = g_pos[3 * p + 2];
    const float dx = g_dir[3 * p + 0];
    const float dy = g_dir[3 * p + 1];
    const float dz = g_dir[3 * p + 2];

    constexpr float scale[16] = {16.f, 21.f, 27.f, 36.f, 48.f, 64.f, 84.f, 111.f,
                                 147.f, 194.f, 256.f, 337.f, 445.f, 588.f, 776.f, 1024.f};

    #pragma unroll
    for (int kb = 0; kb < 4; ++kb) {
        uint32_t w[4];
        #pragma unroll
        for (int l4 = 0; l4 < 4; ++l4) {
            const int lev = kb * 4 + l4;
            const float s = scale[lev];
            const float sx = px * s, sy = py * s, sz = pz * s;
            const float fx = floorf(sx), fy = floorf(sy), fz = floorf(sz);
            const float cx = ceilf(sx),  cy = ceilf(sy),  cz = ceilf(sz);
            const float tx = sx - fx, ty = sy - fy, tz = sz - fz;
            const uint32_t x0 = (uint32_t)fx, x1 = (uint32_t)cx;
            const uint32_t hy0 = (uint32_t)fy * 2654435761u, hy1 = (uint32_t)cy * 2654435761u;
            const uint32_t hz0 = (uint32_t)fz * 805459861u,  hz1 = (uint32_t)cz * 805459861u;
            const uint32_t base = (uint32_t)lev * TBL;
            float e0 = 0.f, e1 = 0.f;
            #pragma unroll
            for (int c = 0; c < 8; ++c) {
                const uint32_t hx = (c & 1) ? x1 : x0;
                const uint32_t hy = (c & 2) ? hy1 : hy0;
                const uint32_t hz = (c & 4) ? hz1 : hz0;
                const uint32_t idx = ((hx ^ hy ^ hz) & TBL_MASK) + base;
                const float2 fv = *reinterpret_cast<const float2*>(g_tab + 2 * (size_t)idx);
                const float wgt = ((c & 1) ? tx : 1.f - tx)
                                * ((c & 2) ? ty : 1.f - ty)
                                * ((c & 4) ? tz : 1.f - tz);
                e0 = fmaf(fv.x, wgt, e0);
                e1 = fmaf(fv.y, wgt, e1);
            }
            w[l4] = pack2(e0, e1);
        }
        *(uint4*)(hcb + m_my * 1024 + (kb * 16 + r_my) * 16) = make_uint4(w[0], w[1], w[2], w[3]);
    }

    {
        const float xx = dx * dx, yy = dy * dy, zz = dz * dz;
        float s[16];
        s[0]  = 0.28209479177387814f;
        s[1]  = 0.4886025119029199f * dy;
        s[2]  = 0.4886025119029199f * dz;
        s[3]  = 0.4886025119029199f * dx;
        s[4]  = 1.0925484305920792f * dx * dy;
        s[5]  = 1.0925484305920792f * dy * dz;
        s[6]  = 0.9461746957575601f * zz - 0.31539156525252f;
        s[7]  = 1.0925484305920792f * dx * dz;
        s[8]  = 0.5462742152960396f * (xx - yy);
        s[9]  = 0.5900435899266435f * dy * (3.f * xx - yy);
        s[10] = 2.890611442640554f * dx * dy * dz;
        s[11] = 0.4570457994644658f * dy * (5.f * zz - 1.f);
        s[12] = 0.3731763325901154f * dz * (5.f * zz - 3.f);
        s[13] = 0.4570457994644658f * dx * (5.f * zz - 1.f);
        s[14] = 1.445305721320277f * dz * (xx - yy);
        s[15] = 0.5900435899266435f * dx * (xx - 3.f * yy);
        *(uint4*)(xinb + m_my * 1024 + (32 + r_my) * 16) =
            make_uint4(pack2(s[0], s[1]), pack2(s[2], s[3]), pack2(s[4], s[5]), pack2(s[6], s[7]));
        *(uint4*)(xinb + m_my * 1024 + (48 + r_my) * 16) =
            make_uint4(pack2(s[8], s[9]), pack2(s[10], s[11]), pack2(s[12], s[13]), pack2(s[14], s[15]));
    }

    const int cl = l & 15;
    const int rg = (l >> 4) << 2;

    {
        f32x4 acc[4][4];
        half8 B[4];
        #pragma unroll
        for (int nt = 0; nt < 4; ++nt) {
            B[nt] = bfrag(g_wd1, 64, 0, nt * 16, l);
            const float b = g_bd1[nt * 16 + cl];
            #pragma unroll
            for (int mt = 0; mt < 4; ++mt) acc[mt][nt] = (f32x4){b, b, b, b};
        }
        #pragma unroll
        for (int mt = 0; mt < 4; ++mt) {
            const half8 A = *(const half8*)(hcb + mt * 1024 + l * 16);
            #pragma unroll
            for (int nt = 0; nt < 4; ++nt) acc[mt][nt] = MFMA(A, B[nt], acc[mt][nt]);
        }
        #pragma unroll
        for (int mt = 0; mt < 4; ++mt)
            #pragma unroll
            for (int nt = 0; nt < 4; ++nt)
                #pragma unroll
                for (int r = 0; r < 4; ++r)
                    st_h(hcb, mt * 16 + rg + r, nt * 16 + cl, acc[mt][nt][r]);
    }

    {
        const half8 B0 = bfrag(g_wd2, 16, 0,  0, l);
        const half8 B1 = bfrag(g_wd2, 16, 32, 0, l);
        const float b = g_bd2[cl];
        #pragma unroll
        for (int mt = 0; mt < 4; ++mt) {
            f32x4 acc = (f32x4){b, b, b, b};
            acc = MFMA(ld_a_h(hcb, mt, 0, l), B0, acc);
            acc = MFMA(ld_a_h(hcb, mt, 1, l), B1, acc);
            #pragma unroll
            for (int r = 0; r < 4; ++r) {
                const int pt = wpt + mt * 16 + rg + r;
                g_out[(size_t)pt * 16 + cl] = acc[r];
                const uint32_t byte = (uint32_t)mt * 1024
                                    + (uint32_t)(((cl >> 3) * 16 + rg + r) * 16) + (uint32_t)(cl & 7) * 2;
                *(uint16_t*)(xinb + byte) = f2h(acc[r]);
            }
        }
    }

    {
        f32x4 acc[4][4];
        half8 B[4];
        #pragma unroll
        for (int nt = 0; nt < 4; ++nt) {
            B[nt] = bfrag(g_wc1, 64, 0, nt * 16, l);
            const float b = g_bc1[nt * 16 + cl];
            #pragma unroll
            for (int mt = 0; mt < 4; ++mt) acc[mt][nt] = (f32x4){b, b, b, b};
        }
        #pragma unroll
        for (int mt = 0; mt < 4; ++mt) {
            const half8 A = *(const half8*)(xinb + mt * 1024 + l * 16);
            #pragma unroll
            for (int nt = 0; nt < 4; ++nt) acc[mt][nt] = MFMA(A, B[nt], acc[mt][nt]);
        }
        #pragma unroll
        for (int mt = 0; mt < 4; ++mt)
            #pragma unroll
            for (int nt = 0; nt < 4; ++nt)
                #pragma unroll
                for (int r = 0; r < 4; ++r)
                    st_h(hcb, mt * 16 + rg + r, nt * 16 + cl, acc[mt][nt][r]);
    }

    {
        f32x4 acc[4][4];
        #pragma unroll
        for (int nt = 0; nt < 4; ++nt) {
            const float b = g_bc2[nt * 16 + cl];
            #pragma unroll
            for (int mt = 0; mt < 4; ++mt) acc[mt][nt] = (f32x4){b, b, b, b};
        }
        #pragma unroll
        for (int kb = 0; kb < 2; ++kb) {
            half8 A[4];
            #pragma unroll
            for (int mt = 0; mt < 4; ++mt) A[mt] = ld_a_h(hcb, mt, kb, l);
            #pragma unroll
            for (int nt = 0; nt < 4; ++nt) {
                const half8 B = bfrag(g_wc2, 64, kb * 32, nt * 16, l);
                #pragma unroll
                for (int mt = 0; mt < 4; ++mt) acc[mt][nt] = MFMA(A[mt], B, acc[mt][nt]);
            }
        }
        #pragma unroll
        for (int mt = 0; mt < 4; ++mt)
            #pragma unroll
            for (int nt = 0; nt < 4; ++nt)
                #pragma unroll
                for (int r = 0; r < 4; ++r)
                    st_h(hcb, mt * 16 + rg + r, nt * 16 + cl, acc[mt][nt][r]);
    }

    {
        const half8 B0 = bfrag3(g_wc3, 0, l);
        const half8 B1 = bfrag3(g_wc3, 32, l);
        const float b = (cl < 3) ? g_bc3[cl] : 0.f;
        #pragma unroll
        for (int mt = 0; mt < 4; ++mt) {
            f32x4 acc = (f32x4){b, b, b, b};
            acc = MFMA(ld_a_h(hcb, mt, 0, l), B0, acc);
            acc = MFMA(ld_a_h(hcb, mt, 1, l), B1, acc);
            if (cl < 3) {
                #pragma unroll
                for (int r = 0; r < 4; ++r) {
                    const int pt = wpt + mt * 16 + rg + r;
                    g_out[(size_t)NPTS * 16 + (size_t)pt * 3 + cl] = 1.f / (1.f + expf(-acc[r]));
                }
            }
        }
    }
}

extern "C" void kernel_launch(void* const* d_in, const int* in_sizes, int n_in,
                              void* d_out, int out_size, void* d_ws, size_t ws_size,
                              hipStream_t stream) {
    if (ws_size >= WS_NEED) {
        uint32_t* tab16 = (uint32_t*)d_ws;
        uint32_t* enc   = (uint32_t*)((char*)d_ws + WS_ENC_OFF);
        convert_tab<<<8192, 256, 0, stream>>>(
            (const float4*)d_in[2], (uint4*)tab16, 2097152);
        gather_enc<<<16384, 256, 0, stream>>>(
            (const float*)d_in[0], tab16, enc);
        nerf_mlp<<<NPTS / 256, 256, 0, stream>>>(
            (const float*)d_in[1], enc,
            (const float*)d_in[3], (const float*)d_in[4],
            (const float*)d_in[5], (const float*)d_in[6],
            (const float*)d_in[7], (const float*)d_in[8],
            (const float*)d_in[9], (const float*)d_in[10],
            (const float*)d_in[11], (const float*)d_in[12],
            (float*)d_out);
    } else {
        nerf_fused<<<NPTS / 256, 256, 0, stream>>>(
            (const float*)d_in[0], (const float*)d_in[1], (const float*)d_in[2],
            (const float*)d_in[3], (const float*)d_in[4],
            (const float*)d_in[5], (const float*)d_in[6],
            (const float*)d_in[7], (const float*)d_in[8],
            (const float*)d_in[9], (const float*)d_in[10],
            (const float*)d_in[11], (const float*)d_in[12],
            (float*)d_out);
    }
}

// Round 7
// 157.107 us; speedup vs baseline: 2.0904x; 1.0152x over previous
//
#include <hip/hip_runtime.h>
#include <stdint.h>

#define NPTS 262144
#define TBL 524288u
#define TBL_MASK 524287u

#define WS_TAB_BYTES (16u * 524288u * 4u)          /* 33,554,432 */
#define WS_ENC_OFF   WS_TAB_BYTES
#define WS_ENC_BYTES (16u * (uint32_t)NPTS * 4u)   /* 16,777,216 */
#define WS_W_OFF     ((size_t)WS_TAB_BYTES + (size_t)WS_ENC_BYTES)
#define WS_W_U32     4736                           /* packed fp16 weights */
#define WS_NEED      (WS_W_OFF + (size_t)WS_W_U32 * 4u)

/* packed-weight u32 offsets inside the weight block */
#define PW_D1 0      /* [16][64] */
#define PW_D2 1024   /* [32][16] */
#define PW_C1 1536   /* [16][64] */
#define PW_C2 2560   /* [32][64] */
#define PW_C3 4608   /* [32][4]  */

typedef __attribute__((ext_vector_type(8))) _Float16 half8;
typedef __attribute__((ext_vector_type(4))) float f32x4;

__device__ const float d_scale[16] = {16.f, 21.f, 27.f, 36.f, 48.f, 64.f, 84.f, 111.f,
                                      147.f, 194.f, 256.f, 337.f, 445.f, 588.f, 776.f, 1024.f};

__device__ __forceinline__ uint16_t f2h(float f) {
    _Float16 h = (_Float16)f;               // v_cvt_f16_f32, RNE
    return __builtin_bit_cast(uint16_t, h);
}
__device__ __forceinline__ uint32_t pack2(float lo, float hi) {
    return (uint32_t)f2h(lo) | ((uint32_t)f2h(hi) << 16);
}
__device__ __forceinline__ float h2f_lo(uint32_t v) {
    return (float)__builtin_bit_cast(_Float16, (uint16_t)(v & 0xffffu));
}
__device__ __forceinline__ float h2f_hi(uint32_t v) {
    return (float)__builtin_bit_cast(_Float16, (uint16_t)(v >> 16));
}

// B-fragment from PRE-PACKED fp16 weights: array is [K/2][N] u32 where
// u32[kp][n] = {W[2kp][n], W[2kp+1][n]}. lane l: k0 = kofs + (l>>4)*8.
__device__ __forceinline__ half8 bfrag_p(const uint32_t* __restrict__ Wp, int N, int kofs, int nofs, int l) {
    const int kp0 = (kofs + ((l >> 4) << 3)) >> 1;
    const uint32_t* p = Wp + (size_t)kp0 * N + (nofs + (l & 15));
    union { uint32_t u[4]; half8 s; } r;
    r.u[0] = p[0 * N];
    r.u[1] = p[1 * N];
    r.u[2] = p[2 * N];
    r.u[3] = p[3 * N];
    return r.s;
}

// wc3 packed as [32][4] u32 (col 3 zero-padded)
__device__ __forceinline__ half8 bfrag3_p(const uint32_t* __restrict__ Wp, int kofs, int l) {
    const int kp0 = (kofs + ((l >> 4) << 3)) >> 1;
    const int n = l & 15;
    union { uint32_t u[4]; half8 s; } r;
    if (n < 3) {
        const uint32_t* p = Wp + (size_t)kp0 * 4 + n;
        r.u[0] = p[0];
        r.u[1] = p[4];
        r.u[2] = p[8];
        r.u[3] = p[12];
    } else {
        r.u[0] = 0; r.u[1] = 0; r.u[2] = 0; r.u[3] = 0;
    }
    return r.s;
}

// ---- f32-source fragment builders (fallback kernel only) ----
__device__ __forceinline__ half8 bfrag(const float* __restrict__ W, int N, int kofs, int nofs, int l) {
    const int k0 = kofs + ((l >> 4) << 3);
    const float* p = W + (size_t)k0 * N + (nofs + (l & 15));
    union { uint32_t u[4]; half8 s; } r;
    r.u[0] = pack2(p[0 * N], p[1 * N]);
    r.u[1] = pack2(p[2 * N], p[3 * N]);
    r.u[2] = pack2(p[4 * N], p[5 * N]);
    r.u[3] = pack2(p[6 * N], p[7 * N]);
    return r.s;
}
__device__ __forceinline__ half8 bfrag3(const float* __restrict__ W, int kofs, int l) {
    const int k0 = kofs + ((l >> 4) << 3);
    const int n = l & 15;
    union { uint32_t u[4]; half8 s; } r;
    if (n < 3) {
        const float* p = W + (size_t)k0 * 3 + n;
        r.u[0] = pack2(p[0],  p[3]);
        r.u[1] = pack2(p[6],  p[9]);
        r.u[2] = pack2(p[12], p[15]);
        r.u[3] = pack2(p[18], p[21]);
    } else {
        r.u[0] = 0; r.u[1] = 0; r.u[2] = 0; r.u[3] = 0;
    }
    return r.s;
}

// A-fragment read from the 64x64 f16 activation tile (XOR-swizzled rows)
__device__ __forceinline__ half8 ld_a_h(const unsigned char* hcb, int mt, int kb, int l) {
    const int row = mt * 16 + (l & 15);
    uint32_t byte = (uint32_t)row * 128 + (uint32_t)kb * 64 + (uint32_t)((l >> 4) << 4);
    byte ^= (uint32_t)(row & 7) << 4;
    return *(const half8*)(hcb + byte);
}

__device__ __forceinline__ void st_h(unsigned char* hcb, int row, int col, float v) {
    uint32_t byte = (uint32_t)row * 128 + (uint32_t)col * 2;
    byte ^= (uint32_t)(row & 7) << 4;
    *(uint16_t*)(hcb + byte) = f2h(fmaxf(v, 0.f));
}

#define MFMA(a, b, c) __builtin_amdgcn_mfma_f32_16x16x32_f16((a), (b), (c), 0, 0, 0)

// ================== k0: table fp32 -> fp16, + weight packing (block 0) ==================
__global__ void __launch_bounds__(256) convert_tab(
    const float4* __restrict__ t, uint4* __restrict__ o, int n4,
    const float* __restrict__ wd1, const float* __restrict__ wd2,
    const float* __restrict__ wc1, const float* __restrict__ wc2,
    const float* __restrict__ wc3, uint32_t* __restrict__ wp)
{
    const int i = blockIdx.x * 256 + threadIdx.x;
    if (i < n4) {
        const float4 a = t[2 * i];
        const float4 b = t[2 * i + 1];
        o[i] = make_uint4(pack2(a.x, a.y), pack2(a.z, a.w),
                          pack2(b.x, b.y), pack2(b.z, b.w));
    }
    if (blockIdx.x == 0) {
        const int tid = threadIdx.x;
        for (int j = tid; j < 1024; j += 256) {  // wd1 [32][64] -> [16][64]
            const int kp = j >> 6, n = j & 63;
            wp[PW_D1 + j] = pack2(wd1[(2 * kp) * 64 + n], wd1[(2 * kp + 1) * 64 + n]);
        }
        for (int j = tid; j < 512; j += 256) {   // wd2 [64][16] -> [32][16]
            const int kp = j >> 4, n = j & 15;
            wp[PW_D2 + j] = pack2(wd2[(2 * kp) * 16 + n], wd2[(2 * kp + 1) * 16 + n]);
        }
        for (int j = tid; j < 1024; j += 256) {  // wc1 [32][64] -> [16][64]
            const int kp = j >> 6, n = j & 63;
            wp[PW_C1 + j] = pack2(wc1[(2 * kp) * 64 + n], wc1[(2 * kp + 1) * 64 + n]);
        }
        for (int j = tid; j < 2048; j += 256) {  // wc2 [64][64] -> [32][64]
            const int kp = j >> 6, n = j & 63;
            wp[PW_C2 + j] = pack2(wc2[(2 * kp) * 64 + n], wc2[(2 * kp + 1) * 64 + n]);
        }
        for (int j = tid; j < 128; j += 256) {   // wc3 [64][3] -> [32][4] (padded)
            const int kp = j >> 2, n = j & 3;
            wp[PW_C3 + j] = (n < 3) ? pack2(wc3[(2 * kp) * 3 + n], wc3[(2 * kp + 1) * 3 + n]) : 0u;
        }
    }
}

// ============ k1: level-phased gather, 2 points/thread (XCD-pinned levels) ============
// x-pair trick: PRIMES[0]==1, so for even x0 the x-floor/x-ceil corners are the
// aligned uint32 pair {idx0&~1, idx0|1} -> one 8B load serves both.
__global__ void __launch_bounds__(256) gather_enc2(
    const float* __restrict__ g_pos,
    const uint32_t* __restrict__ tab16,
    uint32_t* __restrict__ enc)
{
    const int b = blockIdx.x;                       // 8192 blocks
    const int x8 = b & 7;                           // XCD hint
    const int lev = (b >> 12) ? (15 - x8) : x8;     // XCD x: levels x and 15-x
    const int pbase = (((b >> 3) & 511) << 9) + threadIdx.x;  // p0; p1 = p0+256

    const float s = d_scale[lev];
    const uint32_t* t = tab16 + (size_t)lev * TBL;

    // ---- addresses for both points ----
    float tx[2], ty[2], tz[2];
    uint32_t idx0[2][4], idx1[2][4];
    bool odd[2];
    #pragma unroll
    for (int q = 0; q < 2; ++q) {
        const int p = pbase + q * 256;
        const float px = g_pos[3 * p + 0];
        const float py = g_pos[3 * p + 1];
        const float pz = g_pos[3 * p + 2];
        const float sx = px * s, sy = py * s, sz = pz * s;
        const float fx = floorf(sx), fy = floorf(sy), fz = floorf(sz);
        tx[q] = sx - fx; ty[q] = sy - fy; tz[q] = sz - fz;
        const uint32_t x0 = (uint32_t)fx, x1 = (uint32_t)ceilf(sx);
        const uint32_t hy0 = (uint32_t)fy * 2654435761u, hy1 = (uint32_t)ceilf(sy) * 2654435761u;
        const uint32_t hz0 = (uint32_t)fz * 805459861u,  hz1 = (uint32_t)ceilf(sz) * 805459861u;
        odd[q] = (x0 & 1u) != 0u;
        #pragma unroll
        for (int cp = 0; cp < 4; ++cp) {
            const uint32_t hyz = ((cp & 1) ? hy1 : hy0) ^ ((cp & 2) ? hz1 : hz0);
            idx0[q][cp] = (x0 ^ hyz) & TBL_MASK;
            idx1[q][cp] = (x1 ^ hyz) & TBL_MASK;
        }
    }
    // ---- issue all 8 pair loads ----
    uint2 v2[2][4];
    #pragma unroll
    for (int q = 0; q < 2; ++q)
        #pragma unroll
        for (int cp = 0; cp < 4; ++cp)
            v2[q][cp] = *reinterpret_cast<const uint2*>(t + (idx0[q][cp] & ~1u));
    // ---- fixup loads (odd-x0 lanes only) ----
    uint32_t fup[2][4];
    #pragma unroll
    for (int q = 0; q < 2; ++q)
        #pragma unroll
        for (int cp = 0; cp < 4; ++cp)
            fup[q][cp] = odd[q] ? t[idx1[q][cp]] : 0u;
    // ---- combine ----
    #pragma unroll
    for (int q = 0; q < 2; ++q) {
        float e0 = 0.f, e1 = 0.f;
        #pragma unroll
        for (int cp = 0; cp < 4; ++cp) {
            const bool lo = (idx0[q][cp] & 1u) == 0u;
            const uint32_t v0 = lo ? v2[q][cp].x : v2[q][cp].y;
            uint32_t v1 = lo ? v2[q][cp].y : v2[q][cp].x;
            if (odd[q]) v1 = fup[q][cp];
            const float wyz = ((cp & 1) ? ty[q] : 1.f - ty[q]) * ((cp & 2) ? tz[q] : 1.f - tz[q]);
            const float w0 = (1.f - tx[q]) * wyz;
            const float w1 = tx[q] * wyz;
            e0 = fmaf(h2f_lo(v0), w0, fmaf(h2f_lo(v1), w1, e0));
            e1 = fmaf(h2f_hi(v0), w0, fmaf(h2f_hi(v1), w1, e1));
        }
        enc[(size_t)lev * NPTS + pbase + q * 256] = pack2(e0, e1);
    }
}

// ============================ k2: MLP (MFMA, packed fp16 weights) ============================
__global__ void __launch_bounds__(256, 3) nerf_mlp(
    const float* __restrict__ g_dir,
    const uint32_t* __restrict__ enc,
    const uint32_t* __restrict__ wp,
    const float* __restrict__ g_bd1,
    const float* __restrict__ g_bd2,
    const float* __restrict__ g_bc1,
    const float* __restrict__ g_bc2,
    const float* __restrict__ g_bc3,
    float* __restrict__ g_out)
{
    __shared__ __align__(16) unsigned char s_lds[4 * 12288];
    unsigned char* wbase = s_lds + (threadIdx.x >> 6) * 12288;
    unsigned char* hcb  = wbase;
    unsigned char* xinb = wbase + 8192;

    const int l = threadIdx.x & 63;
    const int m_my = l >> 4;
    const int r_my = l & 15;
    const int wpt  = blockIdx.x * 256 + (threadIdx.x & 192);
    const int p    = wpt + l;

    // ---------- enc load -> A-fragment layout in LDS ----------
    #pragma unroll
    for (int kb = 0; kb < 4; ++kb) {
        uint4 w4;
        w4.x = enc[(size_t)(4 * kb + 0) * NPTS + p];
        w4.y = enc[(size_t)(4 * kb + 1) * NPTS + p];
        w4.z = enc[(size_t)(4 * kb + 2) * NPTS + p];
        w4.w = enc[(size_t)(4 * kb + 3) * NPTS + p];
        *(uint4*)(hcb + m_my * 1024 + (kb * 16 + r_my) * 16) = w4;
    }

    const float dx = g_dir[3 * p + 0];
    const float dy = g_dir[3 * p + 1];
    const float dz = g_dir[3 * p + 2];

    // ---------- SH encode -> xin tile k-blocks 2,3 (A-fragment layout) ----------
    {
        const float xx = dx * dx, yy = dy * dy, zz = dz * dz;
        float s[16];
        s[0]  = 0.28209479177387814f;
        s[1]  = 0.4886025119029199f * dy;
        s[2]  = 0.4886025119029199f * dz;
        s[3]  = 0.4886025119029199f * dx;
        s[4]  = 1.0925484305920792f * dx * dy;
        s[5]  = 1.0925484305920792f * dy * dz;
        s[6]  = 0.9461746957575601f * zz - 0.31539156525252f;
        s[7]  = 1.0925484305920792f * dx * dz;
        s[8]  = 0.5462742152960396f * (xx - yy);
        s[9]  = 0.5900435899266435f * dy * (3.f * xx - yy);
        s[10] = 2.890611442640554f * dx * dy * dz;
        s[11] = 0.4570457994644658f * dy * (5.f * zz - 1.f);
        s[12] = 0.3731763325901154f * dz * (5.f * zz - 3.f);
        s[13] = 0.4570457994644658f * dx * (5.f * zz - 1.f);
        s[14] = 1.445305721320277f * dz * (xx - yy);
        s[15] = 0.5900435899266435f * dx * (xx - 3.f * yy);
        *(uint4*)(xinb + m_my * 1024 + (32 + r_my) * 16) =
            make_uint4(pack2(s[0], s[1]), pack2(s[2], s[3]), pack2(s[4], s[5]), pack2(s[6], s[7]));
        *(uint4*)(xinb + m_my * 1024 + (48 + r_my) * 16) =
            make_uint4(pack2(s[8], s[9]), pack2(s[10], s[11]), pack2(s[12], s[13]), pack2(s[14], s[15]));
    }

    const int cl = l & 15;
    const int rg = (l >> 4) << 2;

    // ---------- L1: H = relu(ENC @ Wd1 + bd1)  (64x64, K=32) ----------
    {
        f32x4 acc[4][4];
        half8 B[4];
        #pragma unroll
        for (int nt = 0; nt < 4; ++nt) {
            B[nt] = bfrag_p(wp + PW_D1, 64, 0, nt * 16, l);
            const float b = g_bd1[nt * 16 + cl];
            #pragma unroll
            for (int mt = 0; mt < 4; ++mt) acc[mt][nt] = (f32x4){b, b, b, b};
        }
        #pragma unroll
        for (int mt = 0; mt < 4; ++mt) {
            const half8 A = *(const half8*)(hcb + mt * 1024 + l * 16);
            #pragma unroll
            for (int nt = 0; nt < 4; ++nt) acc[mt][nt] = MFMA(A, B[nt], acc[mt][nt]);
        }
        #pragma unroll
        for (int mt = 0; mt < 4; ++mt)
            #pragma unroll
            for (int nt = 0; nt < 4; ++nt)
                #pragma unroll
                for (int r = 0; r < 4; ++r)
                    st_h(hcb, mt * 16 + rg + r, nt * 16 + cl, acc[mt][nt][r]);
    }

    // ---------- L2: DENS = H @ Wd2 + bd2  (64x16, K=64) -> output + xin kb 0,1 ----------
    {
        const half8 B0 = bfrag_p(wp + PW_D2, 16, 0,  0, l);
        const half8 B1 = bfrag_p(wp + PW_D2, 16, 32, 0, l);
        const float b = g_bd2[cl];
        #pragma unroll
        for (int mt = 0; mt < 4; ++mt) {
            f32x4 acc = (f32x4){b, b, b, b};
            acc = MFMA(ld_a_h(hcb, mt, 0, l), B0, acc);
            acc = MFMA(ld_a_h(hcb, mt, 1, l), B1, acc);
            #pragma unroll
            for (int r = 0; r < 4; ++r) {
                const int pt = wpt + mt * 16 + rg + r;
                g_out[(size_t)pt * 16 + cl] = acc[r];
                const uint32_t byte = (uint32_t)mt * 1024
                                    + (uint32_t)(((cl >> 3) * 16 + rg + r) * 16) + (uint32_t)(cl & 7) * 2;
                *(uint16_t*)(xinb + byte) = f2h(acc[r]);
            }
        }
    }

    // ---------- L3: C1 = relu(XIN @ Wc1 + bc1)  (64x64, K=32) ----------
    {
        f32x4 acc[4][4];
        half8 B[4];
        #pragma unroll
        for (int nt = 0; nt < 4; ++nt) {
            B[nt] = bfrag_p(wp + PW_C1, 64, 0, nt * 16, l);
            const float b = g_bc1[nt * 16 + cl];
            #pragma unroll
            for (int mt = 0; mt < 4; ++mt) acc[mt][nt] = (f32x4){b, b, b, b};
        }
        #pragma unroll
        for (int mt = 0; mt < 4; ++mt) {
            const half8 A = *(const half8*)(xinb + mt * 1024 + l * 16);
            #pragma unroll
            for (int nt = 0; nt < 4; ++nt) acc[mt][nt] = MFMA(A, B[nt], acc[mt][nt]);
        }
        #pragma unroll
        for (int mt = 0; mt < 4; ++mt)
            #pragma unroll
            for (int nt = 0; nt < 4; ++nt)
                #pragma unroll
                for (int r = 0; r < 4; ++r)
                    st_h(hcb, mt * 16 + rg + r, nt * 16 + cl, acc[mt][nt][r]);
    }

    // ---------- L4: C2 = relu(C1 @ Wc2 + bc2)  (64x64, K=64) ----------
    {
        f32x4 acc[4][4];
        #pragma unroll
        for (int nt = 0; nt < 4; ++nt) {
            const float b = g_bc2[nt * 16 + cl];
            #pragma unroll
            for (int mt = 0; mt < 4; ++mt) acc[mt][nt] = (f32x4){b, b, b, b};
        }
        #pragma unroll
        for (int kb = 0; kb < 2; ++kb) {
            half8 A[4];
            #pragma unroll
            for (int mt = 0; mt < 4; ++mt) A[mt] = ld_a_h(hcb, mt, kb, l);
            #pragma unroll
            for (int nt = 0; nt < 4; ++nt) {
                const half8 B = bfrag_p(wp + PW_C2, 64, kb * 32, nt * 16, l);
                #pragma unroll
                for (int mt = 0; mt < 4; ++mt) acc[mt][nt] = MFMA(A[mt], B, acc[mt][nt]);
            }
        }
        #pragma unroll
        for (int mt = 0; mt < 4; ++mt)
            #pragma unroll
            for (int nt = 0; nt < 4; ++nt)
                #pragma unroll
                for (int r = 0; r < 4; ++r)
                    st_h(hcb, mt * 16 + rg + r, nt * 16 + cl, acc[mt][nt][r]);
    }

    // ---------- L5: color = sigmoid(C2 @ Wc3 + bc3)  (64x3 padded to 16, K=64) ----------
    {
        const half8 B0 = bfrag3_p(wp + PW_C3, 0, l);
        const half8 B1 = bfrag3_p(wp + PW_C3, 32, l);
        const float b = (cl < 3) ? g_bc3[cl] : 0.f;
        #pragma unroll
        for (int mt = 0; mt < 4; ++mt) {
            f32x4 acc = (f32x4){b, b, b, b};
            acc = MFMA(ld_a_h(hcb, mt, 0, l), B0, acc);
            acc = MFMA(ld_a_h(hcb, mt, 1, l), B1, acc);
            if (cl < 3) {
                #pragma unroll
                for (int r = 0; r < 4; ++r) {
                    const int pt = wpt + mt * 16 + rg + r;
                    g_out[(size_t)NPTS * 16 + (size_t)pt * 3 + cl] = 1.f / (1.f + expf(-acc[r]));
                }
            }
        }
    }
}

// ================== fallback: round-4 fused kernel (ws too small) ==================
__global__ void __launch_bounds__(256, 3) nerf_fused(
    const float* __restrict__ g_pos,
    const float* __restrict__ g_dir,
    const float* __restrict__ g_tab,
    const float* __restrict__ g_wd1,
    const float* __restrict__ g_bd1,
    const float* __restrict__ g_wd2,
    const float* __restrict__ g_bd2,
    const float* __restrict__ g_wc1,
    const float* __restrict__ g_bc1,
    const float* __restrict__ g_wc2,
    const float* __restrict__ g_bc2,
    const float* __restrict__ g_wc3,
    const float* __restrict__ g_bc3,
    float* __restrict__ g_out)
{
    __shared__ __align__(16) unsigned char s_lds[4 * 12288];
    unsigned char* wbase = s_lds + (threadIdx.x >> 6) * 12288;
    unsigned char* hcb  = wbase;
    unsigned char* xinb = wbase + 8192;

    const int l = threadIdx.x & 63;
    const int m_my = l >> 4;
    const int r_my = l & 15;
    const int wpt  = blockIdx.x * 256 + (threadIdx.x & 192);
    const int p    = wpt + l;

    const float px = g_pos[3 * p + 0];
    const float py = g_pos[3 * p + 1];
    const float pz = g_pos[3 * p + 2];
    const float dx = g_dir[3 * p + 0];
    const float dy = g_dir[3 * p + 1];
    const float dz = g_dir[3 * p + 2];

    constexpr float scale[16] = {16.f, 21.f, 27.f, 36.f, 48.f, 64.f, 84.f, 111.f,
                                 147.f, 194.f, 256.f, 337.f, 445.f, 588.f, 776.f, 1024.f};

    #pragma unroll
    for (int kb = 0; kb < 4; ++kb) {
        uint32_t w[4];
        #pragma unroll
        for (int l4 = 0; l4 < 4; ++l4) {
            const int lev = kb * 4 + l4;
            const float s = scale[lev];
            const float sx = px * s, sy = py * s, sz = pz * s;
            const float fx = floorf(sx), fy = floorf(sy), fz = floorf(sz);
            const float cx = ceilf(sx),  cy = ceilf(sy),  cz = ceilf(sz);
            const float tx = sx - fx, ty = sy - fy, tz = sz - fz;
            const uint32_t x0 = (uint32_t)fx, x1 = (uint32_t)cx;
            const uint32_t hy0 = (uint32_t)fy * 2654435761u, hy1 = (uint32_t)cy * 2654435761u;
            const uint32_t hz0 = (uint32_t)fz * 805459861u,  hz1 = (uint32_t)cz * 805459861u;
            const uint32_t base = (uint32_t)lev * TBL;
            float e0 = 0.f, e1 = 0.f;
            #pragma unroll
            for (int c = 0; c < 8; ++c) {
                const uint32_t hx = (c & 1) ? x1 : x0;
                const uint32_t hy = (c & 2) ? hy1 : hy0;
                const uint32_t hz = (c & 4) ? hz1 : hz0;
                const uint32_t idx = ((hx ^ hy ^ hz) & TBL_MASK) + base;
                const float2 fv = *reinterpret_cast<const float2*>(g_tab + 2 * (size_t)idx);
                const float wgt = ((c & 1) ? tx : 1.f - tx)
                                * ((c & 2) ? ty : 1.f - ty)
                                * ((c & 4) ? tz : 1.f - tz);
                e0 = fmaf(fv.x, wgt, e0);
                e1 = fmaf(fv.y, wgt, e1);
            }
            w[l4] = pack2(e0, e1);
        }
        *(uint4*)(hcb + m_my * 1024 + (kb * 16 + r_my) * 16) = make_uint4(w[0], w[1], w[2], w[3]);
    }

    {
        const float xx = dx * dx, yy = dy * dy, zz = dz * dz;
        float s[16];
        s[0]  = 0.28209479177387814f;
        s[1]  = 0.4886025119029199f * dy;
        s[2]  = 0.4886025119029199f * dz;
        s[3]  = 0.4886025119029199f * dx;
        s[4]  = 1.0925484305920792f * dx * dy;
        s[5]  = 1.0925484305920792f * dy * dz;
        s[6]  = 0.9461746957575601f * zz - 0.31539156525252f;
        s[7]  = 1.0925484305920792f * dx * dz;
        s[8]  = 0.5462742152960396f * (xx - yy);
        s[9]  = 0.5900435899266435f * dy * (3.f * xx - yy);
        s[10] = 2.890611442640554f * dx * dy * dz;
        s[11] = 0.4570457994644658f * dy * (5.f * zz - 1.f);
        s[12] = 0.3731763325901154f * dz * (5.f * zz - 3.f);
        s[13] = 0.4570457994644658f * dx * (5.f * zz - 1.f);
        s[14] = 1.445305721320277f * dz * (xx - yy);
        s[15] = 0.5900435899266435f * dx * (xx - 3.f * yy);
        *(uint4*)(xinb + m_my * 1024 + (32 + r_my) * 16) =
            make_uint4(pack2(s[0], s[1]), pack2(s[2], s[3]), pack2(s[4], s[5]), pack2(s[6], s[7]));
        *(uint4*)(xinb + m_my * 1024 + (48 + r_my) * 16) =
            make_uint4(pack2(s[8], s[9]), pack2(s[10], s[11]), pack2(s[12], s[13]), pack2(s[14], s[15]));
    }

    const int cl = l & 15;
    const int rg = (l >> 4) << 2;

    {
        f32x4 acc[4][4];
        half8 B[4];
        #pragma unroll
        for (int nt = 0; nt < 4; ++nt) {
            B[nt] = bfrag(g_wd1, 64, 0, nt * 16, l);
            const float b = g_bd1[nt * 16 + cl];
            #pragma unroll
            for (int mt = 0; mt < 4; ++mt) acc[mt][nt] = (f32x4){b, b, b, b};
        }
        #pragma unroll
        for (int mt = 0; mt < 4; ++mt) {
            const half8 A = *(const half8*)(hcb + mt * 1024 + l * 16);
            #pragma unroll
            for (int nt = 0; nt < 4; ++nt) acc[mt][nt] = MFMA(A, B[nt], acc[mt][nt]);
        }
        #pragma unroll
        for (int mt = 0; mt < 4; ++mt)
            #pragma unroll
            for (int nt = 0; nt < 4; ++nt)
                #pragma unroll
                for (int r = 0; r < 4; ++r)
                    st_h(hcb, mt * 16 + rg + r, nt * 16 + cl, acc[mt][nt][r]);
    }

    {
        const half8 B0 = bfrag(g_wd2, 16, 0,  0, l);
        const half8 B1 = bfrag(g_wd2, 16, 32, 0, l);
        const float b = g_bd2[cl];
        #pragma unroll
        for (int mt = 0; mt < 4; ++mt) {
            f32x4 acc = (f32x4){b, b, b, b};
            acc = MFMA(ld_a_h(hcb, mt, 0, l), B0, acc);
            acc = MFMA(ld_a_h(hcb, mt, 1, l), B1, acc);
            #pragma unroll
            for (int r = 0; r < 4; ++r) {
                const int pt = wpt + mt * 16 + rg + r;
                g_out[(size_t)pt * 16 + cl] = acc[r];
                const uint32_t byte = (uint32_t)mt * 1024
                                    + (uint32_t)(((cl >> 3) * 16 + rg + r) * 16) + (uint32_t)(cl & 7) * 2;
                *(uint16_t*)(xinb + byte) = f2h(acc[r]);
            }
        }
    }

    {
        f32x4 acc[4][4];
        half8 B[4];
        #pragma unroll
        for (int nt = 0; nt < 4; ++nt) {
            B[nt] = bfrag(g_wc1, 64, 0, nt * 16, l);
            const float b = g_bc1[nt * 16 + cl];
            #pragma unroll
            for (int mt = 0; mt < 4; ++mt) acc[mt][nt] = (f32x4){b, b, b, b};
        }
        #pragma unroll
        for (int mt = 0; mt < 4; ++mt) {
            const half8 A = *(const half8*)(xinb + mt * 1024 + l * 16);
            #pragma unroll
            for (int nt = 0; nt < 4; ++nt) acc[mt][nt] = MFMA(A, B[nt], acc[mt][nt]);
        }
        #pragma unroll
        for (int mt = 0; mt < 4; ++mt)
            #pragma unroll
            for (int nt = 0; nt < 4; ++nt)
                #pragma unroll
                for (int r = 0; r < 4; ++r)
                    st_h(hcb, mt * 16 + rg + r, nt * 16 + cl, acc[mt][nt][r]);
    }

    {
        f32x4 acc[4][4];
        #pragma unroll
        for (int nt = 0; nt < 4; ++nt) {
            const float b = g_bc2[nt * 16 + cl];
            #pragma unroll
            for (int mt = 0; mt < 4; ++mt) acc[mt][nt] = (f32x4){b, b, b, b};
        }
        #pragma unroll
        for (int kb = 0; kb < 2; ++kb) {
            half8 A[4];
            #pragma unroll
            for (int mt = 0; mt < 4; ++mt) A[mt] = ld_a_h(hcb, mt, kb, l);
            #pragma unroll
            for (int nt = 0; nt < 4; ++nt) {
                const half8 B = bfrag(g_wc2, 64, kb * 32, nt * 16, l);
                #pragma unroll
                for (int mt = 0; mt < 4; ++mt) acc[mt][nt] = MFMA(A[mt], B, acc[mt][nt]);
            }
        }
        #pragma unroll
        for (int mt = 0; mt < 4; ++mt)
            #pragma unroll
            for (int nt = 0; nt < 4; ++nt)
                #pragma unroll
                for (int r = 0; r < 4; ++r)
                    st_h(hcb, mt * 16 + rg + r, nt * 16 + cl, acc[mt][nt][r]);
    }

    {
        const half8 B0 = bfrag3(g_wc3, 0, l);
        const half8 B1 = bfrag3(g_wc3, 32, l);
        const float b = (cl < 3) ? g_bc3[cl] : 0.f;
        #pragma unroll
        for (int mt = 0; mt < 4; ++mt) {
            f32x4 acc = (f32x4){b, b, b, b};
            acc = MFMA(ld_a_h(hcb, mt, 0, l), B0, acc);
            acc = MFMA(ld_a_h(hcb, mt, 1, l), B1, acc);
            if (cl < 3) {
                #pragma unroll
                for (int r = 0; r < 4; ++r) {
                    const int pt = wpt + mt * 16 + rg + r;
                    g_out[(size_t)NPTS * 16 + (size_t)pt * 3 + cl] = 1.f / (1.f + expf(-acc[r]));
                }
            }
        }
    }
}

extern "C" void kernel_launch(void* const* d_in, const int* in_sizes, int n_in,
                              void* d_out, int out_size, void* d_ws, size_t ws_size,
                              hipStream_t stream) {
    if (ws_size >= WS_NEED) {
        uint32_t* tab16 = (uint32_t*)d_ws;
        uint32_t* enc   = (uint32_t*)((char*)d_ws + WS_ENC_OFF);
        uint32_t* wpk   = (uint32_t*)((char*)d_ws + WS_W_OFF);
        convert_tab<<<8192, 256, 0, stream>>>(
            (const float4*)d_in[2], (uint4*)tab16, 2097152,
            (const float*)d_in[3], (const float*)d_in[5],
            (const float*)d_in[7], (const float*)d_in[9],
            (const float*)d_in[11], wpk);
        gather_enc2<<<8192, 256, 0, stream>>>(
            (const float*)d_in[0], tab16, enc);
        nerf_mlp<<<NPTS / 256, 256, 0, stream>>>(
            (const float*)d_in[1], enc, wpk,
            (const float*)d_in[4], (const float*)d_in[6],
            (const float*)d_in[8], (const float*)d_in[10],
            (const float*)d_in[12],
            (float*)d_out);
    } else {
        nerf_fused<<<NPTS / 256, 256, 0, stream>>>(
            (const float*)d_in[0], (const float*)d_in[1], (const float*)d_in[2],
            (const float*)d_in[3], (const float*)d_in[4],
            (const float*)d_in[5], (const float*)d_in[6],
            (const float*)d_in[7], (const float*)d_in[8],
            (const float*)d_in[9], (const float*)d_in[10],
            (const float*)d_in[11], (const float*)d_in[12],
            (float*)d_out);
    }
}